// Round 1
// baseline (382.707 us; speedup 1.0000x reference)
//
#include <hip/hip_runtime.h>
#include <stdint.h>

typedef __bf16 bf16;
typedef bf16  bf16x4 __attribute__((ext_vector_type(4)));
typedef bf16  bf16x8 __attribute__((ext_vector_type(8)));
typedef float f32x4  __attribute__((ext_vector_type(4)));

// async global->LDS, 16B per lane, dest = wave-uniform base + lane*16
__device__ __forceinline__ void gll16(const void* g, void* l) {
  __builtin_amdgcn_global_load_lds(
      (__attribute__((address_space(1))) void*)g,
      (__attribute__((address_space(3))) void*)l, 16, 0, 0);
}

// ---------------- prep: transpose fp32 [R][C] -> bf16 [C][R] ----------------
__global__ __launch_bounds__(256) void k_transpose(const float* __restrict__ src,
                                                   bf16* __restrict__ dst, int R, int C) {
  __shared__ float tle[32][33];
  int r0 = blockIdx.x * 32, c0 = blockIdx.y * 32;
  int i = threadIdx.x >> 5, j = threadIdx.x & 31;
#pragma unroll
  for (int p = 0; p < 4; p++) tle[i + 8 * p][j] = src[(size_t)(r0 + i + 8 * p) * C + c0 + j];
  __syncthreads();
#pragma unroll
  for (int p = 0; p < 4; p++)
    dst[(size_t)(c0 + i + 8 * p) * R + r0 + j] = (bf16)tle[j][i + 8 * p];
}

__global__ __launch_bounds__(256) void k_cvt_bf16(const float* __restrict__ src,
                                                  bf16* __restrict__ dst, int n4) {
  int i = blockIdx.x * 256 + threadIdx.x;
  if (i < n4) {
    f32x4 v = *(const f32x4*)(src + (size_t)i * 4);
    bf16x4 o; o[0] = (bf16)v[0]; o[1] = (bf16)v[1]; o[2] = (bf16)v[2]; o[3] = (bf16)v[3];
    *(bf16x4*)(dst + (size_t)i * 4) = o;
  }
}

// ---------------- K1: qkvh[16384][768] = x @ Wt^T (+bias), fused x@Wd row sums ----
__global__ __launch_bounds__(256) void k_qkv(const float* __restrict__ x,
    const bf16* __restrict__ Wt, const float* __restrict__ Wd,
    const float* __restrict__ bq, const float* __restrict__ bk, const float* __restrict__ bv,
    bf16* __restrict__ qkvh, float* __restrict__ gacc) {
  __shared__ bf16 Al[128 * 64];
  __shared__ bf16 Bl[128 * 64];
  __shared__ float red[256];

  const int t = threadIdx.x;
  const int lane = t & 63, w = t >> 6;
  const int rb = blockIdx.x, cb = blockIdx.y;
  const int row0 = rb * 128, n0 = cb * 128;
  const int wr = (w >> 1) * 64, wc = (w & 1) * 64;
  const int l15 = lane & 15, g8 = (lane >> 4) * 8;

  f32x4 acc[4][4] = {};
  float pd = 0.f;

  for (int kb = 0; kb < 2048; kb += 64) {
    f32x4 wv = {};
    if (cb == 0) wv = *(const f32x4*)(Wd + kb + (t & 15) * 4);
#pragma unroll
    for (int p = 0; p < 8; p++) {
      int c = p * 256 + t;
      int r = c >> 4, j0 = (c & 15) * 4;
      f32x4 v = *(const f32x4*)(x + (size_t)(row0 + r) * 2048 + kb + j0);
      if (cb == 0) pd += v[0] * wv[0] + v[1] * wv[1] + v[2] * wv[2] + v[3] * wv[3];
      bf16x4 o; o[0] = (bf16)v[0]; o[1] = (bf16)v[1]; o[2] = (bf16)v[2]; o[3] = (bf16)v[3];
      *(bf16x4*)&Al[r * 64 + j0] = o;
    }
#pragma unroll
    for (int p = 0; p < 4; p++) {
      int c = p * 256 + t;
      int r = c >> 3, j = c & 7;
      gll16(Wt + (size_t)(n0 + r) * 2048 + kb + j * 8, &Bl[(size_t)(p * 256 + (t & ~63)) * 8]);
    }
    __syncthreads();
#pragma unroll
    for (int kk = 0; kk < 64; kk += 32) {
      bf16x8 af[4], bfv[4];
#pragma unroll
      for (int m = 0; m < 4; m++) af[m] = *(const bf16x8*)&Al[(wr + m * 16 + l15) * 64 + kk + g8];
#pragma unroll
      for (int n = 0; n < 4; n++) bfv[n] = *(const bf16x8*)&Bl[(wc + n * 16 + l15) * 64 + kk + g8];
#pragma unroll
      for (int m = 0; m < 4; m++)
#pragma unroll
        for (int n = 0; n < 4; n++)
          acc[m][n] = __builtin_amdgcn_mfma_f32_16x16x32_bf16(af[m], bfv[n], acc[m][n], 0, 0, 0);
    }
    __syncthreads();
  }

  const int sec = cb >> 1;
  const float* bias = sec == 0 ? bq : (sec == 1 ? bk : bv);
#pragma unroll
  for (int m = 0; m < 4; m++)
#pragma unroll
    for (int n = 0; n < 4; n++)
#pragma unroll
      for (int j = 0; j < 4; j++) {
        int r = row0 + wr + m * 16 + (lane >> 4) * 4 + j;
        int c = n0 + wc + n * 16 + l15;
        qkvh[(size_t)r * 768 + c] = (bf16)(acc[m][n][j] + bias[c - sec * 256]);
      }

  if (cb == 0) {
    red[t] = pd;
    __syncthreads();
    if (t < 64) {
      float v2 = red[t] + red[t + 64] + red[t + 128] + red[t + 192];
#pragma unroll
      for (int s = 32; s; s >>= 1) v2 += __shfl_down(v2, s);
      if (t == 0) gacc[rb] = v2;  // rb = bg*4 + slot, deterministic
    }
  }
}

// ---------------- norm: in-place L2-normalize q,k; layernorm v (1 wave / row) ----
__global__ __launch_bounds__(256) void k_norm(bf16* __restrict__ qkvh,
    const float* __restrict__ ln_g, const float* __restrict__ ln_b) {
  const int t = threadIdx.x, lane = t & 63, w = t >> 6;
  const int row = blockIdx.x * 4 + w;
  bf16* rp = qkvh + (size_t)row * 768;

#pragma unroll
  for (int sec = 0; sec < 2; sec++) {
    bf16x4 v = *(bf16x4*)&rp[sec * 256 + lane * 4];
    float f0 = (float)v[0], f1 = (float)v[1], f2 = (float)v[2], f3 = (float)v[3];
    float ss = f0 * f0 + f1 * f1 + f2 * f2 + f3 * f3;
#pragma unroll
    for (int s = 32; s; s >>= 1) ss += __shfl_xor(ss, s);
    float sc = 1.f / fmaxf(sqrtf(ss), 1e-5f);
    bf16x4 o; o[0] = (bf16)(f0 * sc); o[1] = (bf16)(f1 * sc);
    o[2] = (bf16)(f2 * sc); o[3] = (bf16)(f3 * sc);
    *(bf16x4*)&rp[sec * 256 + lane * 4] = o;
  }
  {
    bf16x4 v = *(bf16x4*)&rp[512 + lane * 4];
    float f0 = (float)v[0], f1 = (float)v[1], f2 = (float)v[2], f3 = (float)v[3];
    float s1 = f0 + f1 + f2 + f3;
    float s2 = f0 * f0 + f1 * f1 + f2 * f2 + f3 * f3;
#pragma unroll
    for (int s = 32; s; s >>= 1) { s1 += __shfl_xor(s1, s); s2 += __shfl_xor(s2, s); }
    float mu = s1 * (1.f / 256.f);
    float var = s2 * (1.f / 256.f) - mu * mu;
    float rs = rsqrtf(var + 1e-5f);
    f32x4 g = *(const f32x4*)&ln_g[lane * 4];
    f32x4 b = *(const f32x4*)&ln_b[lane * 4];
    bf16x4 o;
    o[0] = (bf16)((f0 - mu) * rs * g[0] + b[0]);
    o[1] = (bf16)((f1 - mu) * rs * g[1] + b[1]);
    o[2] = (bf16)((f2 - mu) * rs * g[2] + b[2]);
    o[3] = (bf16)((f3 - mu) * rs * g[3] + b[3]);
    *(bf16x4*)&rp[512 + lane * 4] = o;
  }
}

__global__ void k_gamma(const float* __restrict__ gacc, const float* __restrict__ bd,
                        const float* __restrict__ ts, float* __restrict__ gamma) {
  int i = threadIdx.x;
  if (i < 32) {
    float z = (gacc[i * 4] + gacc[i * 4 + 1] + gacc[i * 4 + 2] + gacc[i * 4 + 3]) * (1.f / 512.f)
              + bd[0] + ts[i & 7];
    gamma[i] = 1.f / (1.f + expf(-z));
  }
}

// ------- k_qM: per-group C[n][m] = A(sec)[n][:] @ M[m][:]^T ; optional s = v - C ----
__global__ __launch_bounds__(256) void k_qM(const bf16* __restrict__ qkvh,
    const bf16* __restrict__ M, bf16* __restrict__ out, int sec, int dosub) {
  __shared__ bf16 Al[128 * 64];
  __shared__ bf16 Bl[128 * 64];
  const int t = threadIdx.x, lane = t & 63, w = t >> 6;
  const int bg = blockIdx.x, nb = blockIdx.y, mb = blockIdx.z;
  const int row0 = bg * 512 + nb * 128, m0 = mb * 128;
  const int wr = (w >> 1) * 64, wc = (w & 1) * 64;
  const int l15 = lane & 15, g8 = (lane >> 4) * 8;
  f32x4 acc[4][4] = {};

  for (int kb = 0; kb < 256; kb += 64) {
#pragma unroll
    for (int p = 0; p < 4; p++) {
      int c = p * 256 + t;
      int r = c >> 3, j = c & 7;
      gll16(qkvh + (size_t)(row0 + r) * 768 + sec + kb + j * 8, &Al[(size_t)(p * 256 + (t & ~63)) * 8]);
      gll16(M + (size_t)bg * 65536 + (size_t)(m0 + r) * 256 + kb + j * 8, &Bl[(size_t)(p * 256 + (t & ~63)) * 8]);
    }
    __syncthreads();
#pragma unroll
    for (int kk = 0; kk < 64; kk += 32) {
      bf16x8 af[4], bfv[4];
#pragma unroll
      for (int m = 0; m < 4; m++) af[m] = *(const bf16x8*)&Al[(wr + m * 16 + l15) * 64 + kk + g8];
#pragma unroll
      for (int n = 0; n < 4; n++) bfv[n] = *(const bf16x8*)&Bl[(wc + n * 16 + l15) * 64 + kk + g8];
#pragma unroll
      for (int m = 0; m < 4; m++)
#pragma unroll
        for (int n = 0; n < 4; n++)
          acc[m][n] = __builtin_amdgcn_mfma_f32_16x16x32_bf16(af[m], bfv[n], acc[m][n], 0, 0, 0);
    }
    __syncthreads();
  }
#pragma unroll
  for (int m = 0; m < 4; m++)
#pragma unroll
    for (int n = 0; n < 4; n++)
#pragma unroll
      for (int j = 0; j < 4; j++) {
        int gr = row0 + wr + m * 16 + (lane >> 4) * 4 + j;
        int c = m0 + wc + n * 16 + l15;
        float val = acc[m][n][j];
        if (dosub) val = (float)qkvh[(size_t)gr * 768 + 512 + c] - val;
        out[(size_t)gr * 256 + c] = (bf16)val;
      }
}

// ------- k_deltaM: delta[m][h] = sum_n s[n][m] k[n][h] /512 ; M_next = clip(g*Mp+delta) ----
__global__ __launch_bounds__(256) void k_deltaM(const bf16* __restrict__ s,
    const bf16* __restrict__ qkvh, const float* __restrict__ Mp,
    const float* __restrict__ gamma, float* __restrict__ Mnext, bf16* __restrict__ Mnb) {
  __shared__ bf16 Sl[128 * 64];  // transposed [m][n], XOR-swizzled
  __shared__ bf16 Kl[128 * 64];  // transposed [h][n], XOR-swizzled
  const int t = threadIdx.x, lane = t & 63, w = t >> 6;
  const int bg = blockIdx.x;
  const int m0 = blockIdx.y * 128, h0 = blockIdx.z * 128;
  const int wr = (w >> 1) * 64, wc = (w & 1) * 64;
  const int l15 = lane & 15, g8 = (lane >> 4) * 8;
  f32x4 acc[4][4] = {};

  for (int kb = 0; kb < 512; kb += 64) {
#pragma unroll
    for (int p = 0; p < 4; p++) {
      int c = p * 256 + t;
      int nl = c & 63, j0 = (c >> 6) * 8;
      bf16x8 vs = *(const bf16x8*)(s + (size_t)(bg * 512 + kb + nl) * 256 + m0 + j0);
      bf16x8 vk = *(const bf16x8*)(qkvh + (size_t)(bg * 512 + kb + nl) * 768 + 256 + h0 + j0);
#pragma unroll
      for (int e = 0; e < 8; e++) {
        int m = j0 + e;
        int off = m * 64 + (nl ^ ((m & 7) * 8));
        Sl[off] = vs[e];
        Kl[off] = vk[e];
      }
    }
    __syncthreads();
#pragma unroll
    for (int kk = 0; kk < 64; kk += 32) {
      bf16x8 af[4], bfv[4];
#pragma unroll
      for (int m = 0; m < 4; m++) {
        int ml = wr + m * 16 + l15;
        af[m] = *(const bf16x8*)&Sl[ml * 64 + ((kk + g8) ^ ((ml & 7) * 8))];
      }
#pragma unroll
      for (int n = 0; n < 4; n++) {
        int hl = wc + n * 16 + l15;
        bfv[n] = *(const bf16x8*)&Kl[hl * 64 + ((kk + g8) ^ ((hl & 7) * 8))];
      }
#pragma unroll
      for (int m = 0; m < 4; m++)
#pragma unroll
        for (int n = 0; n < 4; n++)
          acc[m][n] = __builtin_amdgcn_mfma_f32_16x16x32_bf16(af[m], bfv[n], acc[m][n], 0, 0, 0);
    }
    __syncthreads();
  }
  const float gm = gamma[bg];
#pragma unroll
  for (int m = 0; m < 4; m++)
#pragma unroll
    for (int n = 0; n < 4; n++)
#pragma unroll
      for (int j = 0; j < 4; j++) {
        int mg = m0 + wr + m * 16 + (lane >> 4) * 4 + j;
        int hg = h0 + wc + n * 16 + l15;
        size_t idx = (size_t)bg * 65536 + (size_t)mg * 256 + hg;
        float val = gm * Mp[idx] + acc[m][n][j] * (1.f / 512.f);
        val = fminf(10.f, fmaxf(-10.f, val));
        Mnext[idx] = val;
        Mnb[idx] = (bf16)val;
      }
}

// ---------------- k_out: out[16384][2048] = outf @ Wo + bo ----------------
__global__ __launch_bounds__(256) void k_out(const bf16* __restrict__ outf,
    const bf16* __restrict__ WoT, const float* __restrict__ bo, float* __restrict__ out) {
  __shared__ bf16 Al[128 * 64];
  __shared__ bf16 Bl[128 * 64];
  const int t = threadIdx.x, lane = t & 63, w = t >> 6;
  const int row0 = blockIdx.x * 128, n0 = blockIdx.y * 128;
  const int wr = (w >> 1) * 64, wc = (w & 1) * 64;
  const int l15 = lane & 15, g8 = (lane >> 4) * 8;
  f32x4 acc[4][4] = {};

  for (int kb = 0; kb < 256; kb += 64) {
#pragma unroll
    for (int p = 0; p < 4; p++) {
      int c = p * 256 + t;
      int r = c >> 3, j = c & 7;
      gll16(outf + (size_t)(row0 + r) * 256 + kb + j * 8, &Al[(size_t)(p * 256 + (t & ~63)) * 8]);
      gll16(WoT + (size_t)(n0 + r) * 256 + kb + j * 8, &Bl[(size_t)(p * 256 + (t & ~63)) * 8]);
    }
    __syncthreads();
#pragma unroll
    for (int kk = 0; kk < 64; kk += 32) {
      bf16x8 af[4], bfv[4];
#pragma unroll
      for (int m = 0; m < 4; m++) af[m] = *(const bf16x8*)&Al[(wr + m * 16 + l15) * 64 + kk + g8];
#pragma unroll
      for (int n = 0; n < 4; n++) bfv[n] = *(const bf16x8*)&Bl[(wc + n * 16 + l15) * 64 + kk + g8];
#pragma unroll
      for (int m = 0; m < 4; m++)
#pragma unroll
        for (int n = 0; n < 4; n++)
          acc[m][n] = __builtin_amdgcn_mfma_f32_16x16x32_bf16(af[m], bfv[n], acc[m][n], 0, 0, 0);
    }
    __syncthreads();
  }
#pragma unroll
  for (int m = 0; m < 4; m++)
#pragma unroll
    for (int n = 0; n < 4; n++)
#pragma unroll
      for (int j = 0; j < 4; j++) {
        int r = row0 + wr + m * 16 + (lane >> 4) * 4 + j;
        int c = n0 + wc + n * 16 + l15;
        out[(size_t)r * 2048 + c] = acc[m][n][j] + bo[c];
      }
}

extern "C" void kernel_launch(void* const* d_in, const int* in_sizes, int n_in,
                              void* d_out, int out_size, void* d_ws, size_t ws_size,
                              hipStream_t stream) {
  const float* x   = (const float*)d_in[0];
  const float* Mp  = (const float*)d_in[1];
  const float* Wq  = (const float*)d_in[2];
  const float* bq  = (const float*)d_in[3];
  const float* Wk  = (const float*)d_in[4];
  const float* bk  = (const float*)d_in[5];
  const float* Wv  = (const float*)d_in[6];
  const float* bv  = (const float*)d_in[7];
  const float* lng = (const float*)d_in[8];
  const float* lnb = (const float*)d_in[9];
  const float* Wo  = (const float*)d_in[10];
  const float* bo  = (const float*)d_in[11];
  const float* Wd  = (const float*)d_in[12];
  const float* bd  = (const float*)d_in[13];
  const float* ts  = (const float*)d_in[14];

  char* ws = (char*)d_ws;
  bf16*  Wt    = (bf16*)(ws);                // [768][2048]    3 MB
  bf16*  WoT   = (bf16*)(ws + 3145728);      // [2048][256]    1 MB
  bf16*  Mb    = (bf16*)(ws + 4194304);      // [32][256][256] 4 MB
  bf16*  qkvh  = (bf16*)(ws + 8388608);      // [16384][768]  24 MB
  bf16*  sbuf  = (bf16*)(ws + 33554432);     // [16384][256]   8 MB
  bf16*  Mnb   = (bf16*)(ws + 41943040);     // [32][256][256] 4 MB
  bf16*  outf  = (bf16*)(ws + 46137344);     // [16384][256]   8 MB
  float* gacc  = (float*)(ws + 54525952);    // [128]
  float* gamma = (float*)(ws + 54526464);    // [32]

  float* out   = (float*)d_out;              // [16384][2048]
  float* Mnext = (float*)d_out + 33554432;   // [32][256][256]

  dim3 b256(256);
  k_transpose<<<dim3(64, 8),  b256, 0, stream>>>(Wq, Wt,              2048, 256);
  k_transpose<<<dim3(64, 8),  b256, 0, stream>>>(Wk, Wt + 256 * 2048, 2048, 256);
  k_transpose<<<dim3(64, 8),  b256, 0, stream>>>(Wv, Wt + 512 * 2048, 2048, 256);
  k_transpose<<<dim3(8, 64),  b256, 0, stream>>>(Wo, WoT, 256, 2048);
  k_cvt_bf16<<<dim3(2048),    b256, 0, stream>>>(Mp, Mb, 524288);
  k_qkv<<<dim3(128, 6),       b256, 0, stream>>>(x, Wt, Wd, bq, bk, bv, qkvh, gacc);
  k_norm<<<dim3(4096),        b256, 0, stream>>>(qkvh, lng, lnb);
  k_gamma<<<dim3(1), dim3(64), 0, stream>>>(gacc, bd, ts, gamma);
  k_qM<<<dim3(32, 4, 2),      b256, 0, stream>>>(qkvh, Mb, sbuf, 256, 1);
  k_deltaM<<<dim3(32, 2, 2),  b256, 0, stream>>>(sbuf, qkvh, Mp, gamma, Mnext, Mnb);
  k_qM<<<dim3(32, 4, 2),      b256, 0, stream>>>(qkvh, Mnb, outf, 0, 0);
  k_out<<<dim3(128, 16),      b256, 0, stream>>>(outf, WoT, bo, out);
}

// Round 2
// 251.876 us; speedup vs baseline: 1.5194x; 1.5194x over previous
//
#include <hip/hip_runtime.h>
#include <stdint.h>

typedef __bf16 bf16;
typedef bf16  bf16x4 __attribute__((ext_vector_type(4)));
typedef bf16  bf16x8 __attribute__((ext_vector_type(8)));
typedef float f32x4  __attribute__((ext_vector_type(4)));

// async global->LDS, 16B per lane, dest = wave-uniform base + lane*16
__device__ __forceinline__ void gll16(const void* g, void* l) {
  __builtin_amdgcn_global_load_lds(
      (__attribute__((address_space(1))) void*)g,
      (__attribute__((address_space(3))) void*)l, 16, 0, 0);
}

// ---------------- prep: transpose fp32 [R][C] -> bf16 [C][R] ----------------
__global__ __launch_bounds__(256) void k_transpose(const float* __restrict__ src,
                                                   bf16* __restrict__ dst, int R, int C) {
  __shared__ float tle[32][33];
  int r0 = blockIdx.x * 32, c0 = blockIdx.y * 32;
  int i = threadIdx.x >> 5, j = threadIdx.x & 31;
#pragma unroll
  for (int p = 0; p < 4; p++) tle[i + 8 * p][j] = src[(size_t)(r0 + i + 8 * p) * C + c0 + j];
  __syncthreads();
#pragma unroll
  for (int p = 0; p < 4; p++)
    dst[(size_t)(c0 + i + 8 * p) * R + r0 + j] = (bf16)tle[j][i + 8 * p];
}

__global__ __launch_bounds__(256) void k_cvt_bf16(const float* __restrict__ src,
                                                  bf16* __restrict__ dst, int n4) {
  int i = blockIdx.x * 256 + threadIdx.x;
  if (i < n4) {
    f32x4 v = *(const f32x4*)(src + (size_t)i * 4);
    bf16x4 o; o[0] = (bf16)v[0]; o[1] = (bf16)v[1]; o[2] = (bf16)v[2]; o[3] = (bf16)v[3];
    *(bf16x4*)(dst + (size_t)i * 4) = o;
  }
}

// ------- k_cvt_x: x fp32 -> bf16 (row-major, same layout), fused x@Wd row dots ----
__global__ __launch_bounds__(256) void k_cvt_x(const float* __restrict__ x,
    const float* __restrict__ Wd, bf16* __restrict__ xb, float* __restrict__ rowdot) {
  const int t = threadIdx.x, lane = t & 63, w = t >> 6;
  const int row = blockIdx.x * 4 + w;
  const float* xp = x + (size_t)row * 2048;
  bf16* op = xb + (size_t)row * 2048;
  float dot = 0.f;
#pragma unroll
  for (int u = 0; u < 8; u++) {
    int off = u * 256 + lane * 4;
    f32x4 v  = *(const f32x4*)(xp + off);
    f32x4 wv = *(const f32x4*)(Wd + off);
    dot += v[0] * wv[0] + v[1] * wv[1] + v[2] * wv[2] + v[3] * wv[3];
    bf16x4 o; o[0] = (bf16)v[0]; o[1] = (bf16)v[1]; o[2] = (bf16)v[2]; o[3] = (bf16)v[3];
    *(bf16x4*)(op + off) = o;
  }
#pragma unroll
  for (int s = 32; s; s >>= 1) dot += __shfl_xor(dot, s);
  if (lane == 0) rowdot[row] = dot;
}

// ---------------- K1: qkvh[16384][768] = xb @ Wt^T (+bias) — pure m97 structure ----
__global__ __launch_bounds__(256) void k_qkv(const bf16* __restrict__ xb,
    const bf16* __restrict__ Wt,
    const float* __restrict__ bq, const float* __restrict__ bk, const float* __restrict__ bv,
    bf16* __restrict__ qkvh) {
  __shared__ bf16 Al[128 * 64];
  __shared__ bf16 Bl[128 * 64];
  const int t = threadIdx.x, lane = t & 63, w = t >> 6;
  const int cb = blockIdx.y;
  const int row0 = blockIdx.x * 128, n0 = cb * 128;
  const int wr = (w >> 1) * 64, wc = (w & 1) * 64;
  const int l15 = lane & 15, g8 = (lane >> 4) * 8;
  f32x4 acc[4][4] = {};

  for (int kb = 0; kb < 2048; kb += 64) {
#pragma unroll
    for (int p = 0; p < 4; p++) {
      int c = p * 256 + t;
      int r = c >> 3, j = c & 7;
      gll16(xb + (size_t)(row0 + r) * 2048 + kb + j * 8, &Al[(size_t)(p * 256 + (t & ~63)) * 8]);
      gll16(Wt + (size_t)(n0 + r) * 2048 + kb + j * 8, &Bl[(size_t)(p * 256 + (t & ~63)) * 8]);
    }
    __syncthreads();
#pragma unroll
    for (int kk = 0; kk < 64; kk += 32) {
      bf16x8 af[4], bfv[4];
#pragma unroll
      for (int m = 0; m < 4; m++) af[m] = *(const bf16x8*)&Al[(wr + m * 16 + l15) * 64 + kk + g8];
#pragma unroll
      for (int n = 0; n < 4; n++) bfv[n] = *(const bf16x8*)&Bl[(wc + n * 16 + l15) * 64 + kk + g8];
#pragma unroll
      for (int m = 0; m < 4; m++)
#pragma unroll
        for (int n = 0; n < 4; n++)
          acc[m][n] = __builtin_amdgcn_mfma_f32_16x16x32_bf16(af[m], bfv[n], acc[m][n], 0, 0, 0);
    }
    __syncthreads();
  }

  const int sec = cb >> 1;
  const float* bias = sec == 0 ? bq : (sec == 1 ? bk : bv);
#pragma unroll
  for (int m = 0; m < 4; m++)
#pragma unroll
    for (int n = 0; n < 4; n++)
#pragma unroll
      for (int j = 0; j < 4; j++) {
        int r = row0 + wr + m * 16 + (lane >> 4) * 4 + j;
        int c = n0 + wc + n * 16 + l15;
        qkvh[(size_t)r * 768 + c] = (bf16)(acc[m][n][j] + bias[c - sec * 256]);
      }
}

// ---------------- norm: in-place L2-normalize q,k; layernorm v (1 wave / row) ----
__global__ __launch_bounds__(256) void k_norm(bf16* __restrict__ qkvh,
    const float* __restrict__ ln_g, const float* __restrict__ ln_b) {
  const int t = threadIdx.x, lane = t & 63, w = t >> 6;
  const int row = blockIdx.x * 4 + w;
  bf16* rp = qkvh + (size_t)row * 768;

#pragma unroll
  for (int sec = 0; sec < 2; sec++) {
    bf16x4 v = *(bf16x4*)&rp[sec * 256 + lane * 4];
    float f0 = (float)v[0], f1 = (float)v[1], f2 = (float)v[2], f3 = (float)v[3];
    float ss = f0 * f0 + f1 * f1 + f2 * f2 + f3 * f3;
#pragma unroll
    for (int s = 32; s; s >>= 1) ss += __shfl_xor(ss, s);
    float sc = 1.f / fmaxf(sqrtf(ss), 1e-5f);
    bf16x4 o; o[0] = (bf16)(f0 * sc); o[1] = (bf16)(f1 * sc);
    o[2] = (bf16)(f2 * sc); o[3] = (bf16)(f3 * sc);
    *(bf16x4*)&rp[sec * 256 + lane * 4] = o;
  }
  {
    bf16x4 v = *(bf16x4*)&rp[512 + lane * 4];
    float f0 = (float)v[0], f1 = (float)v[1], f2 = (float)v[2], f3 = (float)v[3];
    float s1 = f0 + f1 + f2 + f3;
    float s2 = f0 * f0 + f1 * f1 + f2 * f2 + f3 * f3;
#pragma unroll
    for (int s = 32; s; s >>= 1) { s1 += __shfl_xor(s1, s); s2 += __shfl_xor(s2, s); }
    float mu = s1 * (1.f / 256.f);
    float var = s2 * (1.f / 256.f) - mu * mu;
    float rs = rsqrtf(var + 1e-5f);
    f32x4 g = *(const f32x4*)&ln_g[lane * 4];
    f32x4 b = *(const f32x4*)&ln_b[lane * 4];
    bf16x4 o;
    o[0] = (bf16)((f0 - mu) * rs * g[0] + b[0]);
    o[1] = (bf16)((f1 - mu) * rs * g[1] + b[1]);
    o[2] = (bf16)((f2 - mu) * rs * g[2] + b[2]);
    o[3] = (bf16)((f3 - mu) * rs * g[3] + b[3]);
    *(bf16x4*)&rp[512 + lane * 4] = o;
  }
}

// ---------------- gamma: reduce 512 row-dots per (b,g), sigmoid ----------------
__global__ __launch_bounds__(256) void k_gamma(const float* __restrict__ rowdot,
    const float* __restrict__ bd, const float* __restrict__ ts, float* __restrict__ gamma) {
  __shared__ float red[256];
  const int t = threadIdx.x, bg = blockIdx.x;
  red[t] = rowdot[bg * 512 + t] + rowdot[bg * 512 + 256 + t];
  __syncthreads();
  if (t < 64) {
    float s = red[t] + red[t + 64] + red[t + 128] + red[t + 192];
#pragma unroll
    for (int sh = 32; sh; sh >>= 1) s += __shfl_down(s, sh);
    if (t == 0) gamma[bg] = 1.f / (1.f + expf(-(s * (1.f / 512.f) + bd[0] + ts[bg & 7])));
  }
}

// ------- k_qM: per-group C[n][m] = A(sec)[n][:] @ M[m][:]^T ; optional s = v - C ----
__global__ __launch_bounds__(256) void k_qM(const bf16* __restrict__ qkvh,
    const bf16* __restrict__ M, bf16* __restrict__ out, int sec, int dosub) {
  __shared__ bf16 Al[128 * 64];
  __shared__ bf16 Bl[128 * 64];
  const int t = threadIdx.x, lane = t & 63, w = t >> 6;
  const int bg = blockIdx.x, nb = blockIdx.y, mb = blockIdx.z;
  const int row0 = bg * 512 + nb * 128, m0 = mb * 128;
  const int wr = (w >> 1) * 64, wc = (w & 1) * 64;
  const int l15 = lane & 15, g8 = (lane >> 4) * 8;
  f32x4 acc[4][4] = {};

  for (int kb = 0; kb < 256; kb += 64) {
#pragma unroll
    for (int p = 0; p < 4; p++) {
      int c = p * 256 + t;
      int r = c >> 3, j = c & 7;
      gll16(qkvh + (size_t)(row0 + r) * 768 + sec + kb + j * 8, &Al[(size_t)(p * 256 + (t & ~63)) * 8]);
      gll16(M + (size_t)bg * 65536 + (size_t)(m0 + r) * 256 + kb + j * 8, &Bl[(size_t)(p * 256 + (t & ~63)) * 8]);
    }
    __syncthreads();
#pragma unroll
    for (int kk = 0; kk < 64; kk += 32) {
      bf16x8 af[4], bfv[4];
#pragma unroll
      for (int m = 0; m < 4; m++) af[m] = *(const bf16x8*)&Al[(wr + m * 16 + l15) * 64 + kk + g8];
#pragma unroll
      for (int n = 0; n < 4; n++) bfv[n] = *(const bf16x8*)&Bl[(wc + n * 16 + l15) * 64 + kk + g8];
#pragma unroll
      for (int m = 0; m < 4; m++)
#pragma unroll
        for (int n = 0; n < 4; n++)
          acc[m][n] = __builtin_amdgcn_mfma_f32_16x16x32_bf16(af[m], bfv[n], acc[m][n], 0, 0, 0);
    }
    __syncthreads();
  }
#pragma unroll
  for (int m = 0; m < 4; m++)
#pragma unroll
    for (int n = 0; n < 4; n++)
#pragma unroll
      for (int j = 0; j < 4; j++) {
        int gr = row0 + wr + m * 16 + (lane >> 4) * 4 + j;
        int c = m0 + wc + n * 16 + l15;
        float val = acc[m][n][j];
        if (dosub) val = (float)qkvh[(size_t)gr * 768 + 512 + c] - val;
        out[(size_t)gr * 256 + c] = (bf16)val;
      }
}

// ------- k_deltaM: delta[m][h] = sum_n s[n][m] k[n][h] /512 ; M_next = clip(g*Mp+delta) ----
__global__ __launch_bounds__(256) void k_deltaM(const bf16* __restrict__ s,
    const bf16* __restrict__ qkvh, const float* __restrict__ Mp,
    const float* __restrict__ gamma, float* __restrict__ Mnext, bf16* __restrict__ Mnb) {
  __shared__ bf16 Sl[128 * 64];  // transposed [m][n], XOR-swizzled
  __shared__ bf16 Kl[128 * 64];  // transposed [h][n], XOR-swizzled
  const int t = threadIdx.x, lane = t & 63, w = t >> 6;
  const int bg = blockIdx.x;
  const int m0 = blockIdx.y * 128, h0 = blockIdx.z * 128;
  const int wr = (w >> 1) * 64, wc = (w & 1) * 64;
  const int l15 = lane & 15, g8 = (lane >> 4) * 8;
  f32x4 acc[4][4] = {};

  for (int kb = 0; kb < 512; kb += 64) {
#pragma unroll
    for (int p = 0; p < 4; p++) {
      int c = p * 256 + t;
      int nl = c & 63, j0 = (c >> 6) * 8;
      bf16x8 vs = *(const bf16x8*)(s + (size_t)(bg * 512 + kb + nl) * 256 + m0 + j0);
      bf16x8 vk = *(const bf16x8*)(qkvh + (size_t)(bg * 512 + kb + nl) * 768 + 256 + h0 + j0);
#pragma unroll
      for (int e = 0; e < 8; e++) {
        int m = j0 + e;
        int off = m * 64 + (nl ^ ((m & 7) * 8));
        Sl[off] = vs[e];
        Kl[off] = vk[e];
      }
    }
    __syncthreads();
#pragma unroll
    for (int kk = 0; kk < 64; kk += 32) {
      bf16x8 af[4], bfv[4];
#pragma unroll
      for (int m = 0; m < 4; m++) {
        int ml = wr + m * 16 + l15;
        af[m] = *(const bf16x8*)&Sl[ml * 64 + ((kk + g8) ^ ((ml & 7) * 8))];
      }
#pragma unroll
      for (int n = 0; n < 4; n++) {
        int hl = wc + n * 16 + l15;
        bfv[n] = *(const bf16x8*)&Kl[hl * 64 + ((kk + g8) ^ ((hl & 7) * 8))];
      }
#pragma unroll
      for (int m = 0; m < 4; m++)
#pragma unroll
        for (int n = 0; n < 4; n++)
          acc[m][n] = __builtin_amdgcn_mfma_f32_16x16x32_bf16(af[m], bfv[n], acc[m][n], 0, 0, 0);
    }
    __syncthreads();
  }
  const float gm = gamma[bg];
#pragma unroll
  for (int m = 0; m < 4; m++)
#pragma unroll
    for (int n = 0; n < 4; n++)
#pragma unroll
      for (int j = 0; j < 4; j++) {
        int mg = m0 + wr + m * 16 + (lane >> 4) * 4 + j;
        int hg = h0 + wc + n * 16 + l15;
        size_t idx = (size_t)bg * 65536 + (size_t)mg * 256 + hg;
        float val = gm * Mp[idx] + acc[m][n][j] * (1.f / 512.f);
        val = fminf(10.f, fmaxf(-10.f, val));
        Mnext[idx] = val;
        Mnb[idx] = (bf16)val;
      }
}

// ---------------- k_out: out[16384][2048] = outf @ Wo + bo ----------------
__global__ __launch_bounds__(256) void k_out(const bf16* __restrict__ outf,
    const bf16* __restrict__ WoT, const float* __restrict__ bo, float* __restrict__ out) {
  __shared__ bf16 Al[128 * 64];
  __shared__ bf16 Bl[128 * 64];
  const int t = threadIdx.x, lane = t & 63, w = t >> 6;
  const int row0 = blockIdx.x * 128, n0 = blockIdx.y * 128;
  const int wr = (w >> 1) * 64, wc = (w & 1) * 64;
  const int l15 = lane & 15, g8 = (lane >> 4) * 8;
  f32x4 acc[4][4] = {};

  for (int kb = 0; kb < 256; kb += 64) {
#pragma unroll
    for (int p = 0; p < 4; p++) {
      int c = p * 256 + t;
      int r = c >> 3, j = c & 7;
      gll16(outf + (size_t)(row0 + r) * 256 + kb + j * 8, &Al[(size_t)(p * 256 + (t & ~63)) * 8]);
      gll16(WoT + (size_t)(n0 + r) * 256 + kb + j * 8, &Bl[(size_t)(p * 256 + (t & ~63)) * 8]);
    }
    __syncthreads();
#pragma unroll
    for (int kk = 0; kk < 64; kk += 32) {
      bf16x8 af[4], bfv[4];
#pragma unroll
      for (int m = 0; m < 4; m++) af[m] = *(const bf16x8*)&Al[(wr + m * 16 + l15) * 64 + kk + g8];
#pragma unroll
      for (int n = 0; n < 4; n++) bfv[n] = *(const bf16x8*)&Bl[(wc + n * 16 + l15) * 64 + kk + g8];
#pragma unroll
      for (int m = 0; m < 4; m++)
#pragma unroll
        for (int n = 0; n < 4; n++)
          acc[m][n] = __builtin_amdgcn_mfma_f32_16x16x32_bf16(af[m], bfv[n], acc[m][n], 0, 0, 0);
    }
    __syncthreads();
  }
#pragma unroll
  for (int m = 0; m < 4; m++)
#pragma unroll
    for (int n = 0; n < 4; n++)
#pragma unroll
      for (int j = 0; j < 4; j++) {
        int r = row0 + wr + m * 16 + (lane >> 4) * 4 + j;
        int c = n0 + wc + n * 16 + l15;
        out[(size_t)r * 2048 + c] = acc[m][n][j] + bo[c];
      }
}

extern "C" void kernel_launch(void* const* d_in, const int* in_sizes, int n_in,
                              void* d_out, int out_size, void* d_ws, size_t ws_size,
                              hipStream_t stream) {
  const float* x   = (const float*)d_in[0];
  const float* Mp  = (const float*)d_in[1];
  const float* Wq  = (const float*)d_in[2];
  const float* bq  = (const float*)d_in[3];
  const float* Wk  = (const float*)d_in[4];
  const float* bk  = (const float*)d_in[5];
  const float* Wv  = (const float*)d_in[6];
  const float* bv  = (const float*)d_in[7];
  const float* lng = (const float*)d_in[8];
  const float* lnb = (const float*)d_in[9];
  const float* Wo  = (const float*)d_in[10];
  const float* bo  = (const float*)d_in[11];
  const float* Wd  = (const float*)d_in[12];
  const float* bd  = (const float*)d_in[13];
  const float* ts  = (const float*)d_in[14];

  char* ws = (char*)d_ws;
  bf16*  Wt     = (bf16*)(ws);                // [768][2048]    3 MB
  bf16*  WoT    = (bf16*)(ws + 3145728);      // [2048][256]    1 MB
  bf16*  Mb     = (bf16*)(ws + 4194304);      // [32][256][256] 4 MB
  bf16*  qkvh   = (bf16*)(ws + 8388608);      // [16384][768]  24 MB
  bf16*  sbuf   = (bf16*)(ws + 33554432);     // [16384][256]   8 MB
  bf16*  Mnb    = (bf16*)(ws + 41943040);     // [32][256][256] 4 MB
  bf16*  outf   = (bf16*)(ws + 46137344);     // [16384][256]   8 MB
  float* rowdot = (float*)(ws + 54525952);    // [16384]       64 KB
  float* gamma  = (float*)(ws + 54591488);    // [32]

  float* out   = (float*)d_out;               // [16384][2048]
  float* Mnext = (float*)d_out + 33554432;    // [32][256][256]
  // xb lives in the `out` region of d_out (dead until k_out writes it):
  bf16*  xb    = (bf16*)d_out;                // [16384][2048] bf16, 64 MB

  dim3 b256(256);
  k_cvt_x<<<dim3(4096),       b256, 0, stream>>>(x, Wd, xb, rowdot);
  k_transpose<<<dim3(64, 8),  b256, 0, stream>>>(Wq, Wt,              2048, 256);
  k_transpose<<<dim3(64, 8),  b256, 0, stream>>>(Wk, Wt + 256 * 2048, 2048, 256);
  k_transpose<<<dim3(64, 8),  b256, 0, stream>>>(Wv, Wt + 512 * 2048, 2048, 256);
  k_transpose<<<dim3(8, 64),  b256, 0, stream>>>(Wo, WoT, 256, 2048);
  k_cvt_bf16<<<dim3(2048),    b256, 0, stream>>>(Mp, Mb, 524288);
  k_qkv<<<dim3(128, 6),       b256, 0, stream>>>(xb, Wt, bq, bk, bv, qkvh);
  k_norm<<<dim3(4096),        b256, 0, stream>>>(qkvh, lng, lnb);
  k_gamma<<<dim3(32),         b256, 0, stream>>>(rowdot, bd, ts, gamma);
  k_qM<<<dim3(32, 4, 2),      b256, 0, stream>>>(qkvh, Mb, sbuf, 256, 1);
  k_deltaM<<<dim3(32, 2, 2),  b256, 0, stream>>>(sbuf, qkvh, Mp, gamma, Mnext, Mnb);
  k_qM<<<dim3(32, 4, 2),      b256, 0, stream>>>(qkvh, Mnb, outf, 0, 0);
  k_out<<<dim3(128, 16),      b256, 0, stream>>>(outf, WoT, bo, out);
}

// Round 3
// 251.611 us; speedup vs baseline: 1.5210x; 1.0011x over previous
//
#include <hip/hip_runtime.h>
#include <stdint.h>

typedef __bf16 bf16;
typedef bf16  bf16x4 __attribute__((ext_vector_type(4)));
typedef bf16  bf16x8 __attribute__((ext_vector_type(8)));
typedef float f32x4  __attribute__((ext_vector_type(4)));

// async global->LDS, 16B per lane, dest = wave-uniform base + lane*16
__device__ __forceinline__ void gll16(const void* g, void* l) {
  __builtin_amdgcn_global_load_lds(
      (__attribute__((address_space(1))) void*)g,
      (__attribute__((address_space(3))) void*)l, 16, 0, 0);
}

// ---------------- prep: transpose fp32 [R][C] -> bf16 [C][R] ----------------
__global__ __launch_bounds__(256) void k_transpose(const float* __restrict__ src,
                                                   bf16* __restrict__ dst, int R, int C) {
  __shared__ float tle[32][33];
  int r0 = blockIdx.x * 32, c0 = blockIdx.y * 32;
  int i = threadIdx.x >> 5, j = threadIdx.x & 31;
#pragma unroll
  for (int p = 0; p < 4; p++) tle[i + 8 * p][j] = src[(size_t)(r0 + i + 8 * p) * C + c0 + j];
  __syncthreads();
#pragma unroll
  for (int p = 0; p < 4; p++)
    dst[(size_t)(c0 + i + 8 * p) * R + r0 + j] = (bf16)tle[j][i + 8 * p];
}

__global__ __launch_bounds__(256) void k_cvt_bf16(const float* __restrict__ src,
                                                  bf16* __restrict__ dst, int n4) {
  int i = blockIdx.x * 256 + threadIdx.x;
  if (i < n4) {
    f32x4 v = *(const f32x4*)(src + (size_t)i * 4);
    bf16x4 o; o[0] = (bf16)v[0]; o[1] = (bf16)v[1]; o[2] = (bf16)v[2]; o[3] = (bf16)v[3];
    *(bf16x4*)(dst + (size_t)i * 4) = o;
  }
}

// ------- k_cvt_x: x fp32 -> bf16 (row-major, same layout), fused x@Wd row dots ----
__global__ __launch_bounds__(256) void k_cvt_x(const float* __restrict__ x,
    const float* __restrict__ Wd, bf16* __restrict__ xb, float* __restrict__ rowdot) {
  const int t = threadIdx.x, lane = t & 63, w = t >> 6;
  const int row = blockIdx.x * 4 + w;
  const float* xp = x + (size_t)row * 2048;
  bf16* op = xb + (size_t)row * 2048;
  float dot = 0.f;
#pragma unroll
  for (int u = 0; u < 8; u++) {
    int off = u * 256 + lane * 4;
    f32x4 v  = *(const f32x4*)(xp + off);
    f32x4 wv = *(const f32x4*)(Wd + off);
    dot += v[0] * wv[0] + v[1] * wv[1] + v[2] * wv[2] + v[3] * wv[3];
    bf16x4 o; o[0] = (bf16)v[0]; o[1] = (bf16)v[1]; o[2] = (bf16)v[2]; o[3] = (bf16)v[3];
    *(bf16x4*)(op + off) = o;
  }
#pragma unroll
  for (int s = 32; s; s >>= 1) dot += __shfl_xor(dot, s);
  if (lane == 0) rowdot[row] = dot;
}

// ---- K1: qkvh[16384][768] = xb @ Wt^T (+bias) — 2-phase prefetch, dbuf LDS ----
__global__ __launch_bounds__(256) void k_qkv(const bf16* __restrict__ xb,
    const bf16* __restrict__ Wt,
    const float* __restrict__ bq, const float* __restrict__ bk, const float* __restrict__ bv,
    bf16* __restrict__ qkvh) {
  __shared__ bf16 Al[2][8192];
  __shared__ bf16 Bl[2][8192];
  const int t = threadIdx.x, lane = t & 63, w = t >> 6;
  const int cb = blockIdx.y;
  const int row0 = blockIdx.x * 128, n0 = cb * 128;
  const int wr = (w >> 1) * 64, wc = (w & 1) * 64;
  const int l15 = lane & 15, g8 = (lane >> 4) * 8;
  const int r8 = t >> 3, j8 = (t & 7) * 8;
  f32x4 acc[4][4] = {};

  auto STAGE = [&](int buf, int kb) {
#pragma unroll
    for (int p = 0; p < 4; p++) {
      gll16(xb + (size_t)(row0 + p * 32 + r8) * 2048 + kb + j8, &Al[buf][(p * 256 + (t & ~63)) * 8]);
      gll16(Wt + (size_t)(n0  + p * 32 + r8) * 2048 + kb + j8, &Bl[buf][(p * 256 + (t & ~63)) * 8]);
    }
  };

  STAGE(0, 0);
  __syncthreads();
  int cur = 0;
  for (int it = 0; it < 32; ++it) {
    if (it < 31) STAGE(cur ^ 1, (it + 1) * 64);
#pragma unroll
    for (int kk = 0; kk < 64; kk += 32) {
      bf16x8 af[4], bfv[4];
#pragma unroll
      for (int m = 0; m < 4; m++) af[m] = *(const bf16x8*)&Al[cur][(wr + m * 16 + l15) * 64 + kk + g8];
#pragma unroll
      for (int n = 0; n < 4; n++) bfv[n] = *(const bf16x8*)&Bl[cur][(wc + n * 16 + l15) * 64 + kk + g8];
#pragma unroll
      for (int m = 0; m < 4; m++)
#pragma unroll
        for (int n = 0; n < 4; n++)
          acc[m][n] = __builtin_amdgcn_mfma_f32_16x16x32_bf16(af[m], bfv[n], acc[m][n], 0, 0, 0);
    }
    __syncthreads();
    cur ^= 1;
  }

  const int sec = cb >> 1;
  const float* bias = sec == 0 ? bq : (sec == 1 ? bk : bv);
#pragma unroll
  for (int m = 0; m < 4; m++)
#pragma unroll
    for (int n = 0; n < 4; n++)
#pragma unroll
      for (int j = 0; j < 4; j++) {
        int r = row0 + wr + m * 16 + (lane >> 4) * 4 + j;
        int c = n0 + wc + n * 16 + l15;
        qkvh[(size_t)r * 768 + c] = (bf16)(acc[m][n][j] + bias[c - sec * 256]);
      }
}

// ---------------- norm: in-place L2-normalize q,k; layernorm v (1 wave / row) ----
__global__ __launch_bounds__(256) void k_norm(bf16* __restrict__ qkvh,
    const float* __restrict__ ln_g, const float* __restrict__ ln_b) {
  const int t = threadIdx.x, lane = t & 63, w = t >> 6;
  const int row = blockIdx.x * 4 + w;
  bf16* rp = qkvh + (size_t)row * 768;

#pragma unroll
  for (int sec = 0; sec < 2; sec++) {
    bf16x4 v = *(bf16x4*)&rp[sec * 256 + lane * 4];
    float f0 = (float)v[0], f1 = (float)v[1], f2 = (float)v[2], f3 = (float)v[3];
    float ss = f0 * f0 + f1 * f1 + f2 * f2 + f3 * f3;
#pragma unroll
    for (int s = 32; s; s >>= 1) ss += __shfl_xor(ss, s);
    float sc = 1.f / fmaxf(sqrtf(ss), 1e-5f);
    bf16x4 o; o[0] = (bf16)(f0 * sc); o[1] = (bf16)(f1 * sc);
    o[2] = (bf16)(f2 * sc); o[3] = (bf16)(f3 * sc);
    *(bf16x4*)&rp[sec * 256 + lane * 4] = o;
  }
  {
    bf16x4 v = *(bf16x4*)&rp[512 + lane * 4];
    float f0 = (float)v[0], f1 = (float)v[1], f2 = (float)v[2], f3 = (float)v[3];
    float s1 = f0 + f1 + f2 + f3;
    float s2 = f0 * f0 + f1 * f1 + f2 * f2 + f3 * f3;
#pragma unroll
    for (int s = 32; s; s >>= 1) { s1 += __shfl_xor(s1, s); s2 += __shfl_xor(s2, s); }
    float mu = s1 * (1.f / 256.f);
    float var = s2 * (1.f / 256.f) - mu * mu;
    float rs = rsqrtf(var + 1e-5f);
    f32x4 g = *(const f32x4*)&ln_g[lane * 4];
    f32x4 b = *(const f32x4*)&ln_b[lane * 4];
    bf16x4 o;
    o[0] = (bf16)((f0 - mu) * rs * g[0] + b[0]);
    o[1] = (bf16)((f1 - mu) * rs * g[1] + b[1]);
    o[2] = (bf16)((f2 - mu) * rs * g[2] + b[2]);
    o[3] = (bf16)((f3 - mu) * rs * g[3] + b[3]);
    *(bf16x4*)&rp[512 + lane * 4] = o;
  }
}

// ---------------- gamma: reduce 512 row-dots per (b,g), sigmoid ----------------
__global__ __launch_bounds__(256) void k_gamma(const float* __restrict__ rowdot,
    const float* __restrict__ bd, const float* __restrict__ ts, float* __restrict__ gamma) {
  __shared__ float red[256];
  const int t = threadIdx.x, bg = blockIdx.x;
  red[t] = rowdot[bg * 512 + t] + rowdot[bg * 512 + 256 + t];
  __syncthreads();
  if (t < 64) {
    float s = red[t] + red[t + 64] + red[t + 128] + red[t + 192];
#pragma unroll
    for (int sh = 32; sh; sh >>= 1) s += __shfl_down(s, sh);
    if (t == 0) gamma[bg] = 1.f / (1.f + expf(-(s * (1.f / 512.f) + bd[0] + ts[bg & 7])));
  }
}

// ---- k_qM: per-group C[n][m] = A(sec)[n][:] @ M[m][:]^T ; 512 thr, 2-phase dbuf ----
__global__ __launch_bounds__(512) void k_qM(const bf16* __restrict__ qkvh,
    const bf16* __restrict__ M, bf16* __restrict__ out, int sec, int dosub) {
  __shared__ bf16 Al[2][8192];
  __shared__ bf16 Bl[2][8192];
  const int t = threadIdx.x, lane = t & 63, w = t >> 6;
  const int bg = blockIdx.x, nb = blockIdx.y, mb = blockIdx.z;
  const int row0 = bg * 512 + nb * 128, m0 = mb * 128;
  const int wrow = (w & 1) * 64, wcol = (w >> 1) * 32;
  const int l15 = lane & 15, g8 = (lane >> 4) * 8;
  const int r8 = t >> 3, j8 = (t & 7) * 8;
  f32x4 acc[4][2] = {};

  auto STAGE = [&](int buf, int kb) {
#pragma unroll
    for (int p = 0; p < 2; p++) {
      gll16(qkvh + (size_t)(row0 + p * 64 + r8) * 768 + sec + kb + j8,
            &Al[buf][(p * 512 + (t & ~63)) * 8]);
      gll16(M + (size_t)bg * 65536 + (size_t)(m0 + p * 64 + r8) * 256 + kb + j8,
            &Bl[buf][(p * 512 + (t & ~63)) * 8]);
    }
  };

  STAGE(0, 0);
  __syncthreads();
  int cur = 0;
  for (int it = 0; it < 4; ++it) {
    if (it < 3) STAGE(cur ^ 1, (it + 1) * 64);
#pragma unroll
    for (int kk = 0; kk < 64; kk += 32) {
      bf16x8 af[4], bfv[2];
#pragma unroll
      for (int m = 0; m < 4; m++) af[m] = *(const bf16x8*)&Al[cur][(wrow + m * 16 + l15) * 64 + kk + g8];
#pragma unroll
      for (int n = 0; n < 2; n++) bfv[n] = *(const bf16x8*)&Bl[cur][(wcol + n * 16 + l15) * 64 + kk + g8];
#pragma unroll
      for (int m = 0; m < 4; m++)
#pragma unroll
        for (int n = 0; n < 2; n++)
          acc[m][n] = __builtin_amdgcn_mfma_f32_16x16x32_bf16(af[m], bfv[n], acc[m][n], 0, 0, 0);
    }
    __syncthreads();
    cur ^= 1;
  }
#pragma unroll
  for (int m = 0; m < 4; m++)
#pragma unroll
    for (int n = 0; n < 2; n++)
#pragma unroll
      for (int j = 0; j < 4; j++) {
        int gr = row0 + wrow + m * 16 + (lane >> 4) * 4 + j;
        int c = m0 + wcol + n * 16 + l15;
        float val = acc[m][n][j];
        if (dosub) val = (float)qkvh[(size_t)gr * 768 + 512 + c] - val;
        out[(size_t)gr * 256 + c] = (bf16)val;
      }
}

// ---- k_deltaM: delta[m][h] = sum_n s[n][m] k[n][h] /512 ; 128x64 tiles, 512 thr,
// ---- T14 reg-staged transpose (load early, ds_write after MFMA), XOR-swizzled LDS ----
__global__ __launch_bounds__(512) void k_deltaM(const bf16* __restrict__ s,
    const bf16* __restrict__ qkvh, const float* __restrict__ Mp,
    const float* __restrict__ gamma, float* __restrict__ Mnext, bf16* __restrict__ Mnb) {
  __shared__ bf16 Sl[2][8192];  // [m=128][n=64] transposed, XOR-swizzled
  __shared__ bf16 Kl[2][4096];  // [h=64][n=64]  transposed, XOR-swizzled
  const int t = threadIdx.x, lane = t & 63, w = t >> 6;
  const int bg = blockIdx.x;
  const int m0 = blockIdx.y * 128, h0 = blockIdx.z * 64;
  const int wm = (w & 3) * 32, wh = (w >> 2) * 32;
  const int l15 = lane & 15, g8 = (lane >> 4) * 8;
  const int nl = t & 63, cj = t >> 6;  // cj in 0..7
  f32x4 acc[2][2] = {};

  bf16x8 vs0, vs1, vk;
  auto LOADREGS = [&](int kb) {
    vs0 = *(const bf16x8*)(s + (size_t)(bg * 512 + kb + nl) * 256 + m0 + cj * 8);
    vs1 = *(const bf16x8*)(s + (size_t)(bg * 512 + kb + nl) * 256 + m0 + 64 + cj * 8);
    vk  = *(const bf16x8*)(qkvh + (size_t)(bg * 512 + kb + nl) * 768 + 256 + h0 + cj * 8);
  };
  auto DSWRITE = [&](int buf) {
#pragma unroll
    for (int e = 0; e < 8; e++) {
      int m = cj * 8 + e;
      Sl[buf][m * 64 + (nl ^ ((m & 7) * 8))] = vs0[e];
      int m2 = m + 64;
      Sl[buf][m2 * 64 + (nl ^ ((m2 & 7) * 8))] = vs1[e];
      Kl[buf][m * 64 + (nl ^ ((m & 7) * 8))] = vk[e];
    }
  };

  LOADREGS(0);
  DSWRITE(0);
  __syncthreads();
  int cur = 0;
  for (int it = 0; it < 8; ++it) {
    if (it < 7) LOADREGS((it + 1) * 64);
#pragma unroll
    for (int kk = 0; kk < 64; kk += 32) {
      bf16x8 af[2], bfv[2];
#pragma unroll
      for (int m = 0; m < 2; m++) {
        int ml = wm + m * 16 + l15;
        af[m] = *(const bf16x8*)&Sl[cur][ml * 64 + ((kk + g8) ^ ((ml & 7) * 8))];
      }
#pragma unroll
      for (int n = 0; n < 2; n++) {
        int hl = wh + n * 16 + l15;
        bfv[n] = *(const bf16x8*)&Kl[cur][hl * 64 + ((kk + g8) ^ ((hl & 7) * 8))];
      }
#pragma unroll
      for (int m = 0; m < 2; m++)
#pragma unroll
        for (int n = 0; n < 2; n++)
          acc[m][n] = __builtin_amdgcn_mfma_f32_16x16x32_bf16(af[m], bfv[n], acc[m][n], 0, 0, 0);
    }
    if (it < 7) DSWRITE(cur ^ 1);
    __syncthreads();
    cur ^= 1;
  }
  const float gm = gamma[bg];
#pragma unroll
  for (int m = 0; m < 2; m++)
#pragma unroll
    for (int n = 0; n < 2; n++)
#pragma unroll
      for (int j = 0; j < 4; j++) {
        int mg = m0 + wm + m * 16 + (lane >> 4) * 4 + j;
        int hg = h0 + wh + n * 16 + l15;
        size_t idx = (size_t)bg * 65536 + (size_t)mg * 256 + hg;
        float val = gm * Mp[idx] + acc[m][n][j] * (1.f / 512.f);
        val = fminf(10.f, fmaxf(-10.f, val));
        Mnext[idx] = val;
        Mnb[idx] = (bf16)val;
      }
}

// ---------------- k_out: out[16384][2048] = outf @ Wo + bo — 2-phase dbuf ----
__global__ __launch_bounds__(256) void k_out(const bf16* __restrict__ outf,
    const bf16* __restrict__ WoT, const float* __restrict__ bo, float* __restrict__ out) {
  __shared__ bf16 Al[2][8192];
  __shared__ bf16 Bl[2][8192];
  const int t = threadIdx.x, lane = t & 63, w = t >> 6;
  const int row0 = blockIdx.x * 128, n0 = blockIdx.y * 128;
  const int wr = (w >> 1) * 64, wc = (w & 1) * 64;
  const int l15 = lane & 15, g8 = (lane >> 4) * 8;
  const int r8 = t >> 3, j8 = (t & 7) * 8;
  f32x4 acc[4][4] = {};

  auto STAGE = [&](int buf, int kb) {
#pragma unroll
    for (int p = 0; p < 4; p++) {
      gll16(outf + (size_t)(row0 + p * 32 + r8) * 256 + kb + j8, &Al[buf][(p * 256 + (t & ~63)) * 8]);
      gll16(WoT  + (size_t)(n0  + p * 32 + r8) * 256 + kb + j8, &Bl[buf][(p * 256 + (t & ~63)) * 8]);
    }
  };

  STAGE(0, 0);
  __syncthreads();
  int cur = 0;
  for (int it = 0; it < 4; ++it) {
    if (it < 3) STAGE(cur ^ 1, (it + 1) * 64);
#pragma unroll
    for (int kk = 0; kk < 64; kk += 32) {
      bf16x8 af[4], bfv[4];
#pragma unroll
      for (int m = 0; m < 4; m++) af[m] = *(const bf16x8*)&Al[cur][(wr + m * 16 + l15) * 64 + kk + g8];
#pragma unroll
      for (int n = 0; n < 4; n++) bfv[n] = *(const bf16x8*)&Bl[cur][(wc + n * 16 + l15) * 64 + kk + g8];
#pragma unroll
      for (int m = 0; m < 4; m++)
#pragma unroll
        for (int n = 0; n < 4; n++)
          acc[m][n] = __builtin_amdgcn_mfma_f32_16x16x32_bf16(af[m], bfv[n], acc[m][n], 0, 0, 0);
    }
    __syncthreads();
    cur ^= 1;
  }
#pragma unroll
  for (int m = 0; m < 4; m++)
#pragma unroll
    for (int n = 0; n < 4; n++)
#pragma unroll
      for (int j = 0; j < 4; j++) {
        int r = row0 + wr + m * 16 + (lane >> 4) * 4 + j;
        int c = n0 + wc + n * 16 + l15;
        out[(size_t)r * 2048 + c] = acc[m][n][j] + bo[c];
      }
}

extern "C" void kernel_launch(void* const* d_in, const int* in_sizes, int n_in,
                              void* d_out, int out_size, void* d_ws, size_t ws_size,
                              hipStream_t stream) {
  const float* x   = (const float*)d_in[0];
  const float* Mp  = (const float*)d_in[1];
  const float* Wq  = (const float*)d_in[2];
  const float* bq  = (const float*)d_in[3];
  const float* Wk  = (const float*)d_in[4];
  const float* bk  = (const float*)d_in[5];
  const float* Wv  = (const float*)d_in[6];
  const float* bv  = (const float*)d_in[7];
  const float* lng = (const float*)d_in[8];
  const float* lnb = (const float*)d_in[9];
  const float* Wo  = (const float*)d_in[10];
  const float* bo  = (const float*)d_in[11];
  const float* Wd  = (const float*)d_in[12];
  const float* bd  = (const float*)d_in[13];
  const float* ts  = (const float*)d_in[14];

  char* ws = (char*)d_ws;
  bf16*  Wt     = (bf16*)(ws);                // [768][2048]    3 MB
  bf16*  WoT    = (bf16*)(ws + 3145728);      // [2048][256]    1 MB
  bf16*  Mb     = (bf16*)(ws + 4194304);      // [32][256][256] 4 MB
  bf16*  qkvh   = (bf16*)(ws + 8388608);      // [16384][768]  24 MB
  bf16*  sbuf   = (bf16*)(ws + 33554432);     // [16384][256]   8 MB
  bf16*  Mnb    = (bf16*)(ws + 41943040);     // [32][256][256] 4 MB
  bf16*  outf   = (bf16*)(ws + 46137344);     // [16384][256]   8 MB
  float* rowdot = (float*)(ws + 54525952);    // [16384]       64 KB
  float* gamma  = (float*)(ws + 54591488);    // [32]

  float* out   = (float*)d_out;               // [16384][2048]
  float* Mnext = (float*)d_out + 33554432;    // [32][256][256]
  // xb lives in the `out` region of d_out (dead until k_out writes it):
  bf16*  xb    = (bf16*)d_out;                // [16384][2048] bf16, 64 MB

  dim3 b256(256), b512(512);
  k_cvt_x<<<dim3(4096),       b256, 0, stream>>>(x, Wd, xb, rowdot);
  k_transpose<<<dim3(64, 8),  b256, 0, stream>>>(Wq, Wt,              2048, 256);
  k_transpose<<<dim3(64, 8),  b256, 0, stream>>>(Wk, Wt + 256 * 2048, 2048, 256);
  k_transpose<<<dim3(64, 8),  b256, 0, stream>>>(Wv, Wt + 512 * 2048, 2048, 256);
  k_transpose<<<dim3(8, 64),  b256, 0, stream>>>(Wo, WoT, 256, 2048);
  k_cvt_bf16<<<dim3(2048),    b256, 0, stream>>>(Mp, Mb, 524288);
  k_qkv<<<dim3(128, 6),       b256, 0, stream>>>(xb, Wt, bq, bk, bv, qkvh);
  k_norm<<<dim3(4096),        b256, 0, stream>>>(qkvh, lng, lnb);
  k_gamma<<<dim3(32),         b256, 0, stream>>>(rowdot, bd, ts, gamma);
  k_qM<<<dim3(32, 4, 2),      b512, 0, stream>>>(qkvh, Mb, sbuf, 256, 1);
  k_deltaM<<<dim3(32, 2, 4),  b512, 0, stream>>>(sbuf, qkvh, Mp, gamma, Mnext, Mnb);
  k_qM<<<dim3(32, 4, 2),      b512, 0, stream>>>(qkvh, Mnb, outf, 0, 0);
  k_out<<<dim3(128, 16),      b256, 0, stream>>>(outf, WoT, bo, out);
}

// Round 4
// 215.226 us; speedup vs baseline: 1.7782x; 1.1691x over previous
//
#include <hip/hip_runtime.h>
#include <stdint.h>

typedef __bf16 bf16;
typedef bf16  bf16x4 __attribute__((ext_vector_type(4)));
typedef bf16  bf16x8 __attribute__((ext_vector_type(8)));
typedef float f32x4  __attribute__((ext_vector_type(4)));

// async global->LDS, 16B per lane, dest = wave-uniform base + lane*16
__device__ __forceinline__ void gll16(const void* g, void* l) {
  __builtin_amdgcn_global_load_lds(
      (__attribute__((address_space(1))) void*)g,
      (__attribute__((address_space(3))) void*)l, 16, 0, 0);
}

// ---------------- prep: transpose fp32 [R][C] -> bf16 [C][R] ----------------
__global__ __launch_bounds__(256) void k_transpose(const float* __restrict__ src,
                                                   bf16* __restrict__ dst, int R, int C) {
  __shared__ float tle[32][33];
  int r0 = blockIdx.x * 32, c0 = blockIdx.y * 32;
  int i = threadIdx.x >> 5, j = threadIdx.x & 31;
#pragma unroll
  for (int p = 0; p < 4; p++) tle[i + 8 * p][j] = src[(size_t)(r0 + i + 8 * p) * C + c0 + j];
  __syncthreads();
#pragma unroll
  for (int p = 0; p < 4; p++)
    dst[(size_t)(c0 + i + 8 * p) * R + r0 + j] = (bf16)tle[j][i + 8 * p];
}

__global__ __launch_bounds__(256) void k_cvt_bf16(const float* __restrict__ src,
                                                  bf16* __restrict__ dst, int n4) {
  int i = blockIdx.x * 256 + threadIdx.x;
  if (i < n4) {
    f32x4 v = *(const f32x4*)(src + (size_t)i * 4);
    bf16x4 o; o[0] = (bf16)v[0]; o[1] = (bf16)v[1]; o[2] = (bf16)v[2]; o[3] = (bf16)v[3];
    *(bf16x4*)(dst + (size_t)i * 4) = o;
  }
}

// ------- k_cvt_x: x fp32 -> bf16 (row-major, same layout), fused x@Wd row dots ----
__global__ __launch_bounds__(256) void k_cvt_x(const float* __restrict__ x,
    const float* __restrict__ Wd, bf16* __restrict__ xb, float* __restrict__ rowdot) {
  const int t = threadIdx.x, lane = t & 63, w = t >> 6;
  const int row = blockIdx.x * 4 + w;
  const float* xp = x + (size_t)row * 2048;
  bf16* op = xb + (size_t)row * 2048;
  float dot = 0.f;
#pragma unroll
  for (int u = 0; u < 8; u++) {
    int off = u * 256 + lane * 4;
    f32x4 v  = *(const f32x4*)(xp + off);
    f32x4 wv = *(const f32x4*)(Wd + off);
    dot += v[0] * wv[0] + v[1] * wv[1] + v[2] * wv[2] + v[3] * wv[3];
    bf16x4 o; o[0] = (bf16)v[0]; o[1] = (bf16)v[1]; o[2] = (bf16)v[2]; o[3] = (bf16)v[3];
    *(bf16x4*)(op + off) = o;
  }
#pragma unroll
  for (int s = 32; s; s >>= 1) dot += __shfl_xor(dot, s);
  if (lane == 0) rowdot[row] = dot;
}

// ---- K1: qkvh[16384][768] = xb @ Wt^T (+bias)
// ---- ring-3 counted-vmcnt pipeline (T4), swizzled LDS (T2), BM=128 BN=192 BK=64, 512 thr
__global__ __launch_bounds__(512) void k_qkv(const bf16* __restrict__ xb,
    const bf16* __restrict__ Wt,
    const float* __restrict__ bq, const float* __restrict__ bk, const float* __restrict__ bv,
    bf16* __restrict__ qkvh) {
  __shared__ bf16 As[3][8192];    // 128 rows x 64, swizzled granules: 48 KB
  __shared__ bf16 Bs[3][12288];   // 192 rows x 64, swizzled granules: 72 KB
  const int t = threadIdx.x, lane = t & 63, w = t >> 6;
  const int row0 = blockIdx.x * 128, n0 = blockIdx.y * 192;
  const int wr = (w & 1) * 64, wc = (w >> 1) * 48;
  const int l15 = lane & 15, g8 = (lane >> 4) * 8;
  f32x4 acc[4][3] = {};

  // stage K-tile kt into ring slot `buf`; 2 A-issues + 3 B-issues per thread.
  // LDS dest linear; SOURCE pre-swizzled: slot (r, g) sources granule g^(r&7).
  auto STAGE = [&](int buf, int kt) {
    const int kb = kt * 64;
#pragma unroll
    for (int i = 0; i < 2; i++) {
      int slot = i * 512 + t;
      int r = slot >> 3, gs = (slot & 7) ^ (r & 7);
      gll16(xb + (size_t)(row0 + r) * 2048 + kb + gs * 8, &As[buf][(i * 512 + (t & ~63)) * 8]);
    }
#pragma unroll
    for (int i = 0; i < 3; i++) {
      int slot = i * 512 + t;
      int r = slot >> 3, gs = (slot & 7) ^ (r & 7);
      gll16(Wt + (size_t)(n0 + r) * 2048 + kb + gs * 8, &Bs[buf][(i * 512 + (t & ~63)) * 8]);
    }
  };

  auto COMPUTE = [&](int buf) {
#pragma unroll
    for (int kk = 0; kk < 64; kk += 32) {
      const int q = (kk + g8) >> 3;
      bf16x8 af[4], bfv[3];
#pragma unroll
      for (int m = 0; m < 4; m++) {
        int ra = wr + m * 16 + l15;
        af[m] = *(const bf16x8*)&As[buf][ra * 64 + ((q ^ (ra & 7)) << 3)];
      }
#pragma unroll
      for (int n = 0; n < 3; n++) {
        int rb = wc + n * 16 + l15;
        bfv[n] = *(const bf16x8*)&Bs[buf][rb * 64 + ((q ^ (rb & 7)) << 3)];
      }
#pragma unroll
      for (int m = 0; m < 4; m++)
#pragma unroll
        for (int n = 0; n < 3; n++)
          acc[m][n] = __builtin_amdgcn_mfma_f32_16x16x32_bf16(af[m], bfv[n], acc[m][n], 0, 0, 0);
    }
  };

  const int nt = 32;  // 2048 / 64
  STAGE(0, 0);
  STAGE(1, 1);
  // main loop: stage t+2, wait vmcnt(10) (tiles t+1,t+2 in flight), compute t
  for (int tt = 0; tt < nt - 2; ++tt) {
    STAGE((tt + 2) % 3, tt + 2);
    asm volatile("s_waitcnt vmcnt(10)" ::: "memory");
    __builtin_amdgcn_s_barrier();
    COMPUTE(tt % 3);
    __builtin_amdgcn_s_barrier();
  }
  asm volatile("s_waitcnt vmcnt(5)" ::: "memory");
  __builtin_amdgcn_s_barrier();
  COMPUTE((nt - 2) % 3);
  __builtin_amdgcn_s_barrier();
  asm volatile("s_waitcnt vmcnt(0)" ::: "memory");
  __builtin_amdgcn_s_barrier();
  COMPUTE((nt - 1) % 3);

#pragma unroll
  for (int n = 0; n < 3; n++) {
    int cbase = n0 + wc + n * 16;
    const float* bias = cbase < 256 ? bq : (cbase < 512 ? bk : bv);
    float bv_ = bias[(cbase & 255) + l15];
#pragma unroll
    for (int m = 0; m < 4; m++)
#pragma unroll
      for (int j = 0; j < 4; j++) {
        int r = row0 + wr + m * 16 + (lane >> 4) * 4 + j;
        qkvh[(size_t)r * 768 + cbase + l15] = (bf16)(acc[m][n][j] + bv_);
      }
  }
}

// ---------------- norm: in-place L2-normalize q,k; layernorm v (1 wave / row) ----
__global__ __launch_bounds__(256) void k_norm(bf16* __restrict__ qkvh,
    const float* __restrict__ ln_g, const float* __restrict__ ln_b) {
  const int t = threadIdx.x, lane = t & 63, w = t >> 6;
  const int row = blockIdx.x * 4 + w;
  bf16* rp = qkvh + (size_t)row * 768;

#pragma unroll
  for (int sec = 0; sec < 2; sec++) {
    bf16x4 v = *(bf16x4*)&rp[sec * 256 + lane * 4];
    float f0 = (float)v[0], f1 = (float)v[1], f2 = (float)v[2], f3 = (float)v[3];
    float ss = f0 * f0 + f1 * f1 + f2 * f2 + f3 * f3;
#pragma unroll
    for (int s = 32; s; s >>= 1) ss += __shfl_xor(ss, s);
    float sc = 1.f / fmaxf(sqrtf(ss), 1e-5f);
    bf16x4 o; o[0] = (bf16)(f0 * sc); o[1] = (bf16)(f1 * sc);
    o[2] = (bf16)(f2 * sc); o[3] = (bf16)(f3 * sc);
    *(bf16x4*)&rp[sec * 256 + lane * 4] = o;
  }
  {
    bf16x4 v = *(bf16x4*)&rp[512 + lane * 4];
    float f0 = (float)v[0], f1 = (float)v[1], f2 = (float)v[2], f3 = (float)v[3];
    float s1 = f0 + f1 + f2 + f3;
    float s2 = f0 * f0 + f1 * f1 + f2 * f2 + f3 * f3;
#pragma unroll
    for (int s = 32; s; s >>= 1) { s1 += __shfl_xor(s1, s); s2 += __shfl_xor(s2, s); }
    float mu = s1 * (1.f / 256.f);
    float var = s2 * (1.f / 256.f) - mu * mu;
    float rs = rsqrtf(var + 1e-5f);
    f32x4 g = *(const f32x4*)&ln_g[lane * 4];
    f32x4 b = *(const f32x4*)&ln_b[lane * 4];
    bf16x4 o;
    o[0] = (bf16)((f0 - mu) * rs * g[0] + b[0]);
    o[1] = (bf16)((f1 - mu) * rs * g[1] + b[1]);
    o[2] = (bf16)((f2 - mu) * rs * g[2] + b[2]);
    o[3] = (bf16)((f3 - mu) * rs * g[3] + b[3]);
    *(bf16x4*)&rp[512 + lane * 4] = o;
  }
}

// ---------------- gamma: reduce 512 row-dots per (b,g), sigmoid ----------------
__global__ __launch_bounds__(256) void k_gamma(const float* __restrict__ rowdot,
    const float* __restrict__ bd, const float* __restrict__ ts, float* __restrict__ gamma) {
  __shared__ float red[256];
  const int t = threadIdx.x, bg = blockIdx.x;
  red[t] = rowdot[bg * 512 + t] + rowdot[bg * 512 + 256 + t];
  __syncthreads();
  if (t < 64) {
    float s = red[t] + red[t + 64] + red[t + 128] + red[t + 192];
#pragma unroll
    for (int sh = 32; sh; sh >>= 1) s += __shfl_down(s, sh);
    if (t == 0) gamma[bg] = 1.f / (1.f + expf(-(s * (1.f / 512.f) + bd[0] + ts[bg & 7])));
  }
}

// ---- k_qM: per-group C[n][m] = A(sec)[n][:] @ M[m][:]^T ; 512 thr, 2-phase dbuf ----
__global__ __launch_bounds__(512) void k_qM(const bf16* __restrict__ qkvh,
    const bf16* __restrict__ M, bf16* __restrict__ out, int sec, int dosub) {
  __shared__ bf16 Al[2][8192];
  __shared__ bf16 Bl[2][8192];
  const int t = threadIdx.x, lane = t & 63, w = t >> 6;
  const int bg = blockIdx.x, nb = blockIdx.y, mb = blockIdx.z;
  const int row0 = bg * 512 + nb * 128, m0 = mb * 128;
  const int wrow = (w & 1) * 64, wcol = (w >> 1) * 32;
  const int l15 = lane & 15, g8 = (lane >> 4) * 8;
  const int r8 = t >> 3, j8 = (t & 7) * 8;
  f32x4 acc[4][2] = {};

  auto STAGE = [&](int buf, int kb) {
#pragma unroll
    for (int p = 0; p < 2; p++) {
      gll16(qkvh + (size_t)(row0 + p * 64 + r8) * 768 + sec + kb + j8,
            &Al[buf][(p * 512 + (t & ~63)) * 8]);
      gll16(M + (size_t)bg * 65536 + (size_t)(m0 + p * 64 + r8) * 256 + kb + j8,
            &Bl[buf][(p * 512 + (t & ~63)) * 8]);
    }
  };

  STAGE(0, 0);
  __syncthreads();
  int cur = 0;
  for (int it = 0; it < 4; ++it) {
    if (it < 3) STAGE(cur ^ 1, (it + 1) * 64);
#pragma unroll
    for (int kk = 0; kk < 64; kk += 32) {
      bf16x8 af[4], bfv[2];
#pragma unroll
      for (int m = 0; m < 4; m++) af[m] = *(const bf16x8*)&Al[cur][(wrow + m * 16 + l15) * 64 + kk + g8];
#pragma unroll
      for (int n = 0; n < 2; n++) bfv[n] = *(const bf16x8*)&Bl[cur][(wcol + n * 16 + l15) * 64 + kk + g8];
#pragma unroll
      for (int m = 0; m < 4; m++)
#pragma unroll
        for (int n = 0; n < 2; n++)
          acc[m][n] = __builtin_amdgcn_mfma_f32_16x16x32_bf16(af[m], bfv[n], acc[m][n], 0, 0, 0);
    }
    __syncthreads();
    cur ^= 1;
  }
#pragma unroll
  for (int m = 0; m < 4; m++)
#pragma unroll
    for (int n = 0; n < 2; n++)
#pragma unroll
      for (int j = 0; j < 4; j++) {
        int gr = row0 + wrow + m * 16 + (lane >> 4) * 4 + j;
        int c = m0 + wcol + n * 16 + l15;
        float val = acc[m][n][j];
        if (dosub) val = (float)qkvh[(size_t)gr * 768 + 512 + c] - val;
        out[(size_t)gr * 256 + c] = (bf16)val;
      }
}

// ---- k_deltaM: delta[m][h] = sum_n s[n][m] k[n][h] /512 ; 128x64 tiles, 512 thr,
// ---- T14 reg-staged transpose (load early, ds_write after MFMA), XOR-swizzled LDS ----
__global__ __launch_bounds__(512) void k_deltaM(const bf16* __restrict__ s,
    const bf16* __restrict__ qkvh, const float* __restrict__ Mp,
    const float* __restrict__ gamma, float* __restrict__ Mnext, bf16* __restrict__ Mnb) {
  __shared__ bf16 Sl[2][8192];  // [m=128][n=64] transposed, XOR-swizzled
  __shared__ bf16 Kl[2][4096];  // [h=64][n=64]  transposed, XOR-swizzled
  const int t = threadIdx.x, lane = t & 63, w = t >> 6;
  const int bg = blockIdx.x;
  const int m0 = blockIdx.y * 128, h0 = blockIdx.z * 64;
  const int wm = (w & 3) * 32, wh = (w >> 2) * 32;
  const int l15 = lane & 15, g8 = (lane >> 4) * 8;
  const int nl = t & 63, cj = t >> 6;  // cj in 0..7
  f32x4 acc[2][2] = {};

  bf16x8 vs0, vs1, vk;
  auto LOADREGS = [&](int kb) {
    vs0 = *(const bf16x8*)(s + (size_t)(bg * 512 + kb + nl) * 256 + m0 + cj * 8);
    vs1 = *(const bf16x8*)(s + (size_t)(bg * 512 + kb + nl) * 256 + m0 + 64 + cj * 8);
    vk  = *(const bf16x8*)(qkvh + (size_t)(bg * 512 + kb + nl) * 768 + 256 + h0 + cj * 8);
  };
  auto DSWRITE = [&](int buf) {
#pragma unroll
    for (int e = 0; e < 8; e++) {
      int m = cj * 8 + e;
      Sl[buf][m * 64 + (nl ^ ((m & 7) * 8))] = vs0[e];
      int m2 = m + 64;
      Sl[buf][m2 * 64 + (nl ^ ((m2 & 7) * 8))] = vs1[e];
      Kl[buf][m * 64 + (nl ^ ((m & 7) * 8))] = vk[e];
    }
  };

  LOADREGS(0);
  DSWRITE(0);
  __syncthreads();
  int cur = 0;
  for (int it = 0; it < 8; ++it) {
    if (it < 7) LOADREGS((it + 1) * 64);
#pragma unroll
    for (int kk = 0; kk < 64; kk += 32) {
      bf16x8 af[2], bfv[2];
#pragma unroll
      for (int m = 0; m < 2; m++) {
        int ml = wm + m * 16 + l15;
        af[m] = *(const bf16x8*)&Sl[cur][ml * 64 + ((kk + g8) ^ ((ml & 7) * 8))];
      }
#pragma unroll
      for (int n = 0; n < 2; n++) {
        int hl = wh + n * 16 + l15;
        bfv[n] = *(const bf16x8*)&Kl[cur][hl * 64 + ((kk + g8) ^ ((hl & 7) * 8))];
      }
#pragma unroll
      for (int m = 0; m < 2; m++)
#pragma unroll
        for (int n = 0; n < 2; n++)
          acc[m][n] = __builtin_amdgcn_mfma_f32_16x16x32_bf16(af[m], bfv[n], acc[m][n], 0, 0, 0);
    }
    if (it < 7) DSWRITE(cur ^ 1);
    __syncthreads();
    cur ^= 1;
  }
  const float gm = gamma[bg];
#pragma unroll
  for (int m = 0; m < 2; m++)
#pragma unroll
    for (int n = 0; n < 2; n++)
#pragma unroll
      for (int j = 0; j < 4; j++) {
        int mg = m0 + wm + m * 16 + (lane >> 4) * 4 + j;
        int hg = h0 + wh + n * 16 + l15;
        size_t idx = (size_t)bg * 65536 + (size_t)mg * 256 + hg;
        float val = gm * Mp[idx] + acc[m][n][j] * (1.f / 512.f);
        val = fminf(10.f, fmaxf(-10.f, val));
        Mnext[idx] = val;
        Mnb[idx] = (bf16)val;
      }
}

// ---------------- k_out: out[16384][2048] = outf @ Wo + bo — 2-phase dbuf ----
__global__ __launch_bounds__(256) void k_out(const bf16* __restrict__ outf,
    const bf16* __restrict__ WoT, const float* __restrict__ bo, float* __restrict__ out) {
  __shared__ bf16 Al[2][8192];
  __shared__ bf16 Bl[2][8192];
  const int t = threadIdx.x, lane = t & 63, w = t >> 6;
  const int row0 = blockIdx.x * 128, n0 = blockIdx.y * 128;
  const int wr = (w >> 1) * 64, wc = (w & 1) * 64;
  const int l15 = lane & 15, g8 = (lane >> 4) * 8;
  const int r8 = t >> 3, j8 = (t & 7) * 8;
  f32x4 acc[4][4] = {};

  auto STAGE = [&](int buf, int kb) {
#pragma unroll
    for (int p = 0; p < 4; p++) {
      gll16(outf + (size_t)(row0 + p * 32 + r8) * 256 + kb + j8, &Al[buf][(p * 256 + (t & ~63)) * 8]);
      gll16(WoT  + (size_t)(n0  + p * 32 + r8) * 256 + kb + j8, &Bl[buf][(p * 256 + (t & ~63)) * 8]);
    }
  };

  STAGE(0, 0);
  __syncthreads();
  int cur = 0;
  for (int it = 0; it < 4; ++it) {
    if (it < 3) STAGE(cur ^ 1, (it + 1) * 64);
#pragma unroll
    for (int kk = 0; kk < 64; kk += 32) {
      bf16x8 af[4], bfv[4];
#pragma unroll
      for (int m = 0; m < 4; m++) af[m] = *(const bf16x8*)&Al[cur][(wr + m * 16 + l15) * 64 + kk + g8];
#pragma unroll
      for (int n = 0; n < 4; n++) bfv[n] = *(const bf16x8*)&Bl[cur][(wc + n * 16 + l15) * 64 + kk + g8];
#pragma unroll
      for (int m = 0; m < 4; m++)
#pragma unroll
        for (int n = 0; n < 4; n++)
          acc[m][n] = __builtin_amdgcn_mfma_f32_16x16x32_bf16(af[m], bfv[n], acc[m][n], 0, 0, 0);
    }
    __syncthreads();
    cur ^= 1;
  }
#pragma unroll
  for (int m = 0; m < 4; m++)
#pragma unroll
    for (int n = 0; n < 4; n++)
#pragma unroll
      for (int j = 0; j < 4; j++) {
        int r = row0 + wr + m * 16 + (lane >> 4) * 4 + j;
        int c = n0 + wc + n * 16 + l15;
        out[(size_t)r * 2048 + c] = acc[m][n][j] + bo[c];
      }
}

extern "C" void kernel_launch(void* const* d_in, const int* in_sizes, int n_in,
                              void* d_out, int out_size, void* d_ws, size_t ws_size,
                              hipStream_t stream) {
  const float* x   = (const float*)d_in[0];
  const float* Mp  = (const float*)d_in[1];
  const float* Wq  = (const float*)d_in[2];
  const float* bq  = (const float*)d_in[3];
  const float* Wk  = (const float*)d_in[4];
  const float* bk  = (const float*)d_in[5];
  const float* Wv  = (const float*)d_in[6];
  const float* bv  = (const float*)d_in[7];
  const float* lng = (const float*)d_in[8];
  const float* lnb = (const float*)d_in[9];
  const float* Wo  = (const float*)d_in[10];
  const float* bo  = (const float*)d_in[11];
  const float* Wd  = (const float*)d_in[12];
  const float* bd  = (const float*)d_in[13];
  const float* ts  = (const float*)d_in[14];

  char* ws = (char*)d_ws;
  bf16*  Wt     = (bf16*)(ws);                // [768][2048]    3 MB
  bf16*  WoT    = (bf16*)(ws + 3145728);      // [2048][256]    1 MB
  bf16*  Mb     = (bf16*)(ws + 4194304);      // [32][256][256] 4 MB
  bf16*  qkvh   = (bf16*)(ws + 8388608);      // [16384][768]  24 MB
  bf16*  sbuf   = (bf16*)(ws + 33554432);     // [16384][256]   8 MB
  bf16*  Mnb    = (bf16*)(ws + 41943040);     // [32][256][256] 4 MB
  bf16*  outf   = (bf16*)(ws + 46137344);     // [16384][256]   8 MB
  float* rowdot = (float*)(ws + 54525952);    // [16384]       64 KB
  float* gamma  = (float*)(ws + 54591488);    // [32]

  float* out   = (float*)d_out;               // [16384][2048]
  float* Mnext = (float*)d_out + 33554432;    // [32][256][256]
  // xb lives in the `out` region of d_out (dead until k_out writes it):
  bf16*  xb    = (bf16*)d_out;                // [16384][2048] bf16, 64 MB

  dim3 b256(256), b512(512);
  k_cvt_x<<<dim3(4096),       b256, 0, stream>>>(x, Wd, xb, rowdot);
  k_transpose<<<dim3(64, 8),  b256, 0, stream>>>(Wq, Wt,              2048, 256);
  k_transpose<<<dim3(64, 8),  b256, 0, stream>>>(Wk, Wt + 256 * 2048, 2048, 256);
  k_transpose<<<dim3(64, 8),  b256, 0, stream>>>(Wv, Wt + 512 * 2048, 2048, 256);
  k_transpose<<<dim3(8, 64),  b256, 0, stream>>>(Wo, WoT, 256, 2048);
  k_cvt_bf16<<<dim3(2048),    b256, 0, stream>>>(Mp, Mb, 524288);
  k_qkv<<<dim3(128, 4),       b512, 0, stream>>>(xb, Wt, bq, bk, bv, qkvh);
  k_norm<<<dim3(4096),        b256, 0, stream>>>(qkvh, lng, lnb);
  k_gamma<<<dim3(32),         b256, 0, stream>>>(rowdot, bd, ts, gamma);
  k_qM<<<dim3(32, 4, 2),      b512, 0, stream>>>(qkvh, Mb, sbuf, 256, 1);
  k_deltaM<<<dim3(32, 2, 4),  b512, 0, stream>>>(sbuf, qkvh, Mp, gamma, Mnext, Mnb);
  k_qM<<<dim3(32, 4, 2),      b512, 0, stream>>>(qkvh, Mnb, outf, 0, 0);
  k_out<<<dim3(128, 16),      b256, 0, stream>>>(outf, WoT, bo, out);
}

// Round 5
// 199.380 us; speedup vs baseline: 1.9195x; 1.0795x over previous
//
#include <hip/hip_runtime.h>
#include <stdint.h>

typedef __bf16 bf16;
typedef bf16  bf16x4 __attribute__((ext_vector_type(4)));
typedef bf16  bf16x8 __attribute__((ext_vector_type(8)));
typedef float f32x4  __attribute__((ext_vector_type(4)));

// async global->LDS, 16B per lane, dest = wave-uniform base + lane*16
__device__ __forceinline__ void gll16(const void* g, void* l) {
  __builtin_amdgcn_global_load_lds(
      (__attribute__((address_space(1))) void*)g,
      (__attribute__((address_space(3))) void*)l, 16, 0, 0);
}

// ---- k_prep: all weight transposes + Mp cvt + x cvt (+rowdot) in ONE launch ----
__global__ __launch_bounds__(256) void k_prep(
    const float* __restrict__ Wq, const float* __restrict__ Wk, const float* __restrict__ Wv,
    const float* __restrict__ Wo, const float* __restrict__ Mp, const float* __restrict__ x,
    const float* __restrict__ Wd,
    bf16* __restrict__ Wt, bf16* __restrict__ WoT, bf16* __restrict__ Mb,
    bf16* __restrict__ xb, float* __restrict__ rowdot) {
  __shared__ float tle[32][33];
  const int id = blockIdx.x, t = threadIdx.x;
  if (id < 1536) {
    // transpose W{q,k,v} [2048][256] -> Wt + sec*256*2048  [256][2048]
    const float* src = id < 512 ? Wq : (id < 1024 ? Wk : Wv);
    bf16* dst = Wt + (size_t)(id / 512) * 256 * 2048;
    int lid = id & 511;
    int r0 = (lid >> 3) * 32, c0 = (lid & 7) * 32;
    int i = t >> 5, j = t & 31;
#pragma unroll
    for (int p = 0; p < 4; p++) tle[i + 8 * p][j] = src[(size_t)(r0 + i + 8 * p) * 256 + c0 + j];
    __syncthreads();
#pragma unroll
    for (int p = 0; p < 4; p++)
      dst[(size_t)(c0 + i + 8 * p) * 2048 + r0 + j] = (bf16)tle[j][i + 8 * p];
  } else if (id < 2048) {
    // transpose Wo [256][2048] -> WoT [2048][256]
    int lid = id - 1536;
    int r0 = (lid >> 6) * 32, c0 = (lid & 63) * 32;
    int i = t >> 5, j = t & 31;
#pragma unroll
    for (int p = 0; p < 4; p++) tle[i + 8 * p][j] = Wo[(size_t)(r0 + i + 8 * p) * 2048 + c0 + j];
    __syncthreads();
#pragma unroll
    for (int p = 0; p < 4; p++)
      WoT[(size_t)(c0 + i + 8 * p) * 256 + r0 + j] = (bf16)tle[j][i + 8 * p];
  } else if (id < 4096) {
    // cvt Mp fp32 -> Mb bf16 (x4 per thread)
    int i = (id - 2048) * 256 + t;
    f32x4 v = *(const f32x4*)(Mp + (size_t)i * 4);
    bf16x4 o; o[0] = (bf16)v[0]; o[1] = (bf16)v[1]; o[2] = (bf16)v[2]; o[3] = (bf16)v[3];
    *(bf16x4*)(Mb + (size_t)i * 4) = o;
  } else {
    // cvt x fp32 -> xb bf16 + fused x@Wd row dots (1 wave / row)
    const int lane = t & 63, w = t >> 6;
    const int row = (id - 4096) * 4 + w;
    const float* xp = x + (size_t)row * 2048;
    bf16* op = xb + (size_t)row * 2048;
    float dot = 0.f;
#pragma unroll
    for (int u = 0; u < 8; u++) {
      int off = u * 256 + lane * 4;
      f32x4 v  = *(const f32x4*)(xp + off);
      f32x4 wv = *(const f32x4*)(Wd + off);
      dot += v[0] * wv[0] + v[1] * wv[1] + v[2] * wv[2] + v[3] * wv[3];
      bf16x4 o; o[0] = (bf16)v[0]; o[1] = (bf16)v[1]; o[2] = (bf16)v[2]; o[3] = (bf16)v[3];
      *(bf16x4*)(op + off) = o;
    }
#pragma unroll
    for (int s = 32; s; s >>= 1) dot += __shfl_xor(dot, s);
    if (lane == 0) rowdot[row] = dot;
  }
}

// ---- K1: qkvh[16384][768] = xb @ Wt^T, fused bias + q/k L2-norm + v layernorm
// ---- BM=128 BN=256 BK=32, 512 thr (2Mx4N waves), ring-2 counted vmcnt, swizzled LDS
__global__ __launch_bounds__(512) void k_qkv(const bf16* __restrict__ xb,
    const bf16* __restrict__ Wt,
    const float* __restrict__ bq, const float* __restrict__ bk, const float* __restrict__ bv,
    const float* __restrict__ lng, const float* __restrict__ lnb,
    bf16* __restrict__ qkvh) {
  __shared__ bf16 As[2][4096];   // 128 x 32, 64B rows of 4 granules
  __shared__ bf16 Bs[2][8192];   // 256 x 32
  __shared__ float red1[512], red2[512];
  const int t = threadIdx.x, lane = t & 63, w = t >> 6;
  const int sec = blockIdx.y;
  const int row0 = blockIdx.x * 128, n0 = sec * 256;
  const int wr = (w & 1) * 64, wc = (w >> 1) * 64;
  const int l15 = lane & 15, ql = lane >> 4;
  f32x4 acc[4][4] = {};

  // swizzle: physical granule p at (row r, slot g) holds logical granule g^((r>>1)&3)
  auto STAGE = [&](int buf, int kt) {
    const int kb = kt * 32;
    { int r = t >> 2, gl = (t & 3) ^ ((r >> 1) & 3);
      gll16(xb + (size_t)(row0 + r) * 2048 + kb + gl * 8, &As[buf][(t & ~63) * 8]); }
#pragma unroll
    for (int i = 0; i < 2; i++) {
      int s = i * 512 + t;
      int r = s >> 2, gl = (s & 3) ^ ((r >> 1) & 3);
      gll16(Wt + (size_t)(n0 + r) * 2048 + kb + gl * 8, &Bs[buf][(i * 512 + (t & ~63)) * 8]);
    }
  };
  auto COMPUTE = [&](int buf) {
    bf16x8 af[4], bfv[4];
#pragma unroll
    for (int m = 0; m < 4; m++) {
      int ra = wr + m * 16 + l15;
      af[m] = *(const bf16x8*)&As[buf][ra * 32 + ((ql ^ ((ra >> 1) & 3)) << 3)];
    }
#pragma unroll
    for (int n = 0; n < 4; n++) {
      int rb = wc + n * 16 + l15;
      bfv[n] = *(const bf16x8*)&Bs[buf][rb * 32 + ((ql ^ ((rb >> 1) & 3)) << 3)];
    }
#pragma unroll
    for (int m = 0; m < 4; m++)
#pragma unroll
      for (int n = 0; n < 4; n++)
        acc[m][n] = __builtin_amdgcn_mfma_f32_16x16x32_bf16(af[m], bfv[n], acc[m][n], 0, 0, 0);
  };

  STAGE(0, 0);
  int cur = 0;
  for (int tt = 0; tt < 64; ++tt) {
    if (tt < 63) {
      STAGE(cur ^ 1, tt + 1);
      asm volatile("s_waitcnt vmcnt(3)" ::: "memory");
    } else {
      asm volatile("s_waitcnt vmcnt(0)" ::: "memory");
    }
    __builtin_amdgcn_s_barrier();
    COMPUTE(cur);
    __builtin_amdgcn_s_barrier();
    cur ^= 1;
  }

  // ---- fused epilogue: bias + row-wise norm over the block's full 256 cols ----
  __syncthreads();
  const float* bias = sec == 0 ? bq : (sec == 1 ? bk : bv);
#pragma unroll
  for (int m = 0; m < 4; m++)
#pragma unroll
    for (int j = 0; j < 4; j++) {
      float p1 = 0.f, p2 = 0.f;
#pragma unroll
      for (int n = 0; n < 4; n++) {
        float v = acc[m][n][j] + bias[wc + n * 16 + l15];
        p1 += v; p2 += v * v;
      }
#pragma unroll
      for (int mask = 8; mask; mask >>= 1) {
        p1 += __shfl_xor(p1, mask);
        p2 += __shfl_xor(p2, mask);
      }
      if (l15 == 0) {
        int rl = wr + m * 16 + ql * 4 + j;
        red1[rl * 4 + (w >> 1)] = p1;
        red2[rl * 4 + (w >> 1)] = p2;
      }
    }
  __syncthreads();
#pragma unroll
  for (int m = 0; m < 4; m++)
#pragma unroll
    for (int j = 0; j < 4; j++) {
      int rl = wr + m * 16 + ql * 4 + j;
      float s1 = red1[rl * 4] + red1[rl * 4 + 1] + red1[rl * 4 + 2] + red1[rl * 4 + 3];
      float s2 = red2[rl * 4] + red2[rl * 4 + 1] + red2[rl * 4 + 2] + red2[rl * 4 + 3];
      float sc = 1.f / fmaxf(sqrtf(s2), 1e-5f);
      float mu = s1 * (1.f / 256.f);
      float rs = rsqrtf(s2 * (1.f / 256.f) - mu * mu + 1e-5f);
#pragma unroll
      for (int n = 0; n < 4; n++) {
        int c = wc + n * 16 + l15;
        float v = acc[m][n][j] + bias[c];
        float o = sec < 2 ? v * sc : (v - mu) * rs * lng[c] + lnb[c];
        qkvh[(size_t)(row0 + rl) * 768 + n0 + c] = (bf16)o;
      }
    }
}

// ---------------- gamma: reduce 512 row-dots per (b,g), sigmoid ----------------
__global__ __launch_bounds__(256) void k_gamma(const float* __restrict__ rowdot,
    const float* __restrict__ bd, const float* __restrict__ ts, float* __restrict__ gamma) {
  __shared__ float red[256];
  const int t = threadIdx.x, bg = blockIdx.x;
  red[t] = rowdot[bg * 512 + t] + rowdot[bg * 512 + 256 + t];
  __syncthreads();
  if (t < 64) {
    float s = red[t] + red[t + 64] + red[t + 128] + red[t + 192];
#pragma unroll
    for (int sh = 32; sh; sh >>= 1) s += __shfl_down(s, sh);
    if (t == 0) gamma[bg] = 1.f / (1.f + expf(-(s * (1.f / 512.f) + bd[0] + ts[bg & 7])));
  }
}

// ---- k_qM: per-group C[n][m] = A(sec)[n][:] @ M[m][:]^T ; optional s = v - C
// ---- BK=32 ring-2 counted vmcnt, swizzled LDS, 512 thr
__global__ __launch_bounds__(512) void k_qM(const bf16* __restrict__ qkvh,
    const bf16* __restrict__ M, bf16* __restrict__ out, int sec, int dosub) {
  __shared__ bf16 Al[2][4096];
  __shared__ bf16 Bl[2][4096];
  const int t = threadIdx.x, lane = t & 63, w = t >> 6;
  const int bg = blockIdx.x, nb = blockIdx.y, mb = blockIdx.z;
  const int row0 = bg * 512 + nb * 128, m0 = mb * 128;
  const int wrow = (w & 1) * 64, wcol = (w >> 1) * 32;
  const int l15 = lane & 15, ql = lane >> 4;
  f32x4 acc[4][2] = {};

  auto STAGE = [&](int buf, int kt) {
    const int kb = kt * 32;
    int r = t >> 2, gl = (t & 3) ^ ((r >> 1) & 3);
    gll16(qkvh + (size_t)(row0 + r) * 768 + sec + kb + gl * 8, &Al[buf][(t & ~63) * 8]);
    gll16(M + (size_t)bg * 65536 + (size_t)(m0 + r) * 256 + kb + gl * 8, &Bl[buf][(t & ~63) * 8]);
  };
  auto COMPUTE = [&](int buf) {
    bf16x8 af[4], bfv[2];
#pragma unroll
    for (int m = 0; m < 4; m++) {
      int ra = wrow + m * 16 + l15;
      af[m] = *(const bf16x8*)&Al[buf][ra * 32 + ((ql ^ ((ra >> 1) & 3)) << 3)];
    }
#pragma unroll
    for (int n = 0; n < 2; n++) {
      int rb = wcol + n * 16 + l15;
      bfv[n] = *(const bf16x8*)&Bl[buf][rb * 32 + ((ql ^ ((rb >> 1) & 3)) << 3)];
    }
#pragma unroll
    for (int m = 0; m < 4; m++)
#pragma unroll
      for (int n = 0; n < 2; n++)
        acc[m][n] = __builtin_amdgcn_mfma_f32_16x16x32_bf16(af[m], bfv[n], acc[m][n], 0, 0, 0);
  };

  STAGE(0, 0);
  int cur = 0;
  for (int tt = 0; tt < 8; ++tt) {
    if (tt < 7) {
      STAGE(cur ^ 1, tt + 1);
      asm volatile("s_waitcnt vmcnt(2)" ::: "memory");
    } else {
      asm volatile("s_waitcnt vmcnt(0)" ::: "memory");
    }
    __builtin_amdgcn_s_barrier();
    COMPUTE(cur);
    __builtin_amdgcn_s_barrier();
    cur ^= 1;
  }
#pragma unroll
  for (int m = 0; m < 4; m++)
#pragma unroll
    for (int n = 0; n < 2; n++)
#pragma unroll
      for (int j = 0; j < 4; j++) {
        int gr = row0 + wrow + m * 16 + ql * 4 + j;
        int c = m0 + wcol + n * 16 + l15;
        float val = acc[m][n][j];
        if (dosub) val = (float)qkvh[(size_t)gr * 768 + 512 + c] - val;
        out[(size_t)gr * 256 + c] = (bf16)val;
      }
}

// ---- k_deltaM: delta[m][h] = sum_n s[n][m] k[n][h] /512 ; M_next = clip(g*Mp+delta)
__global__ __launch_bounds__(512) void k_deltaM(const bf16* __restrict__ s,
    const bf16* __restrict__ qkvh, const float* __restrict__ Mp,
    const float* __restrict__ gamma, float* __restrict__ Mnext, bf16* __restrict__ Mnb) {
  __shared__ bf16 Sl[2][8192];  // [m=128][n=64] transposed, XOR-swizzled
  __shared__ bf16 Kl[2][4096];  // [h=64][n=64]  transposed, XOR-swizzled
  const int t = threadIdx.x, lane = t & 63, w = t >> 6;
  const int bg = blockIdx.x;
  const int m0 = blockIdx.y * 128, h0 = blockIdx.z * 64;
  const int wm = (w & 3) * 32, wh = (w >> 2) * 32;
  const int l15 = lane & 15, g8 = (lane >> 4) * 8;
  const int nl = t & 63, cj = t >> 6;  // cj in 0..7
  f32x4 acc[2][2] = {};

  bf16x8 vs0, vs1, vk;
  auto LOADREGS = [&](int kb) {
    vs0 = *(const bf16x8*)(s + (size_t)(bg * 512 + kb + nl) * 256 + m0 + cj * 8);
    vs1 = *(const bf16x8*)(s + (size_t)(bg * 512 + kb + nl) * 256 + m0 + 64 + cj * 8);
    vk  = *(const bf16x8*)(qkvh + (size_t)(bg * 512 + kb + nl) * 768 + 256 + h0 + cj * 8);
  };
  auto DSWRITE = [&](int buf) {
#pragma unroll
    for (int e = 0; e < 8; e++) {
      int m = cj * 8 + e;
      Sl[buf][m * 64 + (nl ^ ((m & 7) * 8))] = vs0[e];
      int m2 = m + 64;
      Sl[buf][m2 * 64 + (nl ^ ((m2 & 7) * 8))] = vs1[e];
      Kl[buf][m * 64 + (nl ^ ((m & 7) * 8))] = vk[e];
    }
  };

  LOADREGS(0);
  DSWRITE(0);
  __syncthreads();
  int cur = 0;
  for (int it = 0; it < 8; ++it) {
    if (it < 7) LOADREGS((it + 1) * 64);
#pragma unroll
    for (int kk = 0; kk < 64; kk += 32) {
      bf16x8 af[2], bfv[2];
#pragma unroll
      for (int m = 0; m < 2; m++) {
        int ml = wm + m * 16 + l15;
        af[m] = *(const bf16x8*)&Sl[cur][ml * 64 + ((kk + g8) ^ ((ml & 7) * 8))];
      }
#pragma unroll
      for (int n = 0; n < 2; n++) {
        int hl = wh + n * 16 + l15;
        bfv[n] = *(const bf16x8*)&Kl[cur][hl * 64 + ((kk + g8) ^ ((hl & 7) * 8))];
      }
#pragma unroll
      for (int m = 0; m < 2; m++)
#pragma unroll
        for (int n = 0; n < 2; n++)
          acc[m][n] = __builtin_amdgcn_mfma_f32_16x16x32_bf16(af[m], bfv[n], acc[m][n], 0, 0, 0);
    }
    if (it < 7) DSWRITE(cur ^ 1);
    __syncthreads();
    cur ^= 1;
  }
  const float gm = gamma[bg];
#pragma unroll
  for (int m = 0; m < 2; m++)
#pragma unroll
    for (int n = 0; n < 2; n++)
#pragma unroll
      for (int j = 0; j < 4; j++) {
        int mg = m0 + wm + m * 16 + (lane >> 4) * 4 + j;
        int hg = h0 + wh + n * 16 + l15;
        size_t idx = (size_t)bg * 65536 + (size_t)mg * 256 + hg;
        float val = gm * Mp[idx] + acc[m][n][j] * (1.f / 512.f);
        val = fminf(10.f, fmaxf(-10.f, val));
        Mnext[idx] = val;
        Mnb[idx] = (bf16)val;
      }
}

// ---- k_out: out[16384][2048] = outf @ Wo + bo
// ---- BM=128 BN=256 BK=32, ring-2 counted vmcnt, swizzled, 512 thr
__global__ __launch_bounds__(512) void k_out(const bf16* __restrict__ outf,
    const bf16* __restrict__ WoT, const float* __restrict__ bo, float* __restrict__ out) {
  __shared__ bf16 As[2][4096];
  __shared__ bf16 Bs[2][8192];
  const int t = threadIdx.x, lane = t & 63, w = t >> 6;
  const int row0 = blockIdx.x * 128, n0 = blockIdx.y * 256;
  const int wr = (w & 1) * 64, wc = (w >> 1) * 64;
  const int l15 = lane & 15, ql = lane >> 4;
  f32x4 acc[4][4] = {};

  auto STAGE = [&](int buf, int kt) {
    const int kb = kt * 32;
    { int r = t >> 2, gl = (t & 3) ^ ((r >> 1) & 3);
      gll16(outf + (size_t)(row0 + r) * 256 + kb + gl * 8, &As[buf][(t & ~63) * 8]); }
#pragma unroll
    for (int i = 0; i < 2; i++) {
      int s = i * 512 + t;
      int r = s >> 2, gl = (s & 3) ^ ((r >> 1) & 3);
      gll16(WoT + (size_t)(n0 + r) * 256 + kb + gl * 8, &Bs[buf][(i * 512 + (t & ~63)) * 8]);
    }
  };
  auto COMPUTE = [&](int buf) {
    bf16x8 af[4], bfv[4];
#pragma unroll
    for (int m = 0; m < 4; m++) {
      int ra = wr + m * 16 + l15;
      af[m] = *(const bf16x8*)&As[buf][ra * 32 + ((ql ^ ((ra >> 1) & 3)) << 3)];
    }
#pragma unroll
    for (int n = 0; n < 4; n++) {
      int rb = wc + n * 16 + l15;
      bfv[n] = *(const bf16x8*)&Bs[buf][rb * 32 + ((ql ^ ((rb >> 1) & 3)) << 3)];
    }
#pragma unroll
    for (int m = 0; m < 4; m++)
#pragma unroll
      for (int n = 0; n < 4; n++)
        acc[m][n] = __builtin_amdgcn_mfma_f32_16x16x32_bf16(af[m], bfv[n], acc[m][n], 0, 0, 0);
  };

  STAGE(0, 0);
  int cur = 0;
  for (int tt = 0; tt < 8; ++tt) {
    if (tt < 7) {
      STAGE(cur ^ 1, tt + 1);
      asm volatile("s_waitcnt vmcnt(3)" ::: "memory");
    } else {
      asm volatile("s_waitcnt vmcnt(0)" ::: "memory");
    }
    __builtin_amdgcn_s_barrier();
    COMPUTE(cur);
    __builtin_amdgcn_s_barrier();
    cur ^= 1;
  }
#pragma unroll
  for (int m = 0; m < 4; m++)
#pragma unroll
    for (int n = 0; n < 4; n++)
#pragma unroll
      for (int j = 0; j < 4; j++) {
        int r = row0 + wr + m * 16 + ql * 4 + j;
        int c = n0 + wc + n * 16 + l15;
        out[(size_t)r * 2048 + c] = acc[m][n][j] + bo[c];
      }
}

extern "C" void kernel_launch(void* const* d_in, const int* in_sizes, int n_in,
                              void* d_out, int out_size, void* d_ws, size_t ws_size,
                              hipStream_t stream) {
  const float* x   = (const float*)d_in[0];
  const float* Mp  = (const float*)d_in[1];
  const float* Wq  = (const float*)d_in[2];
  const float* bq  = (const float*)d_in[3];
  const float* Wk  = (const float*)d_in[4];
  const float* bk  = (const float*)d_in[5];
  const float* Wv  = (const float*)d_in[6];
  const float* bv  = (const float*)d_in[7];
  const float* lng = (const float*)d_in[8];
  const float* lnb = (const float*)d_in[9];
  const float* Wo  = (const float*)d_in[10];
  const float* bo  = (const float*)d_in[11];
  const float* Wd  = (const float*)d_in[12];
  const float* bd  = (const float*)d_in[13];
  const float* ts  = (const float*)d_in[14];

  char* ws = (char*)d_ws;
  bf16*  Wt     = (bf16*)(ws);                // [768][2048]    3 MB
  bf16*  WoT    = (bf16*)(ws + 3145728);      // [2048][256]    1 MB
  bf16*  Mb     = (bf16*)(ws + 4194304);      // [32][256][256] 4 MB
  bf16*  qkvh   = (bf16*)(ws + 8388608);      // [16384][768]  24 MB
  bf16*  sbuf   = (bf16*)(ws + 33554432);     // [16384][256]   8 MB
  bf16*  Mnb    = (bf16*)(ws + 41943040);     // [32][256][256] 4 MB
  bf16*  outf   = (bf16*)(ws + 46137344);     // [16384][256]   8 MB
  float* rowdot = (float*)(ws + 54525952);    // [16384]       64 KB
  float* gamma  = (float*)(ws + 54591488);    // [32]

  float* out   = (float*)d_out;               // [16384][2048]
  float* Mnext = (float*)d_out + 33554432;    // [32][256][256]
  // xb lives in the `out` region of d_out (dead until k_out writes it):
  bf16*  xb    = (bf16*)d_out;                // [16384][2048] bf16, 64 MB

  dim3 b256(256), b512(512);
  k_prep<<<dim3(8192),       b256, 0, stream>>>(Wq, Wk, Wv, Wo, Mp, x, Wd, Wt, WoT, Mb, xb, rowdot);
  k_qkv<<<dim3(128, 3),      b512, 0, stream>>>(xb, Wt, bq, bk, bv, lng, lnb, qkvh);
  k_gamma<<<dim3(32),        b256, 0, stream>>>(rowdot, bd, ts, gamma);
  k_qM<<<dim3(32, 4, 2),     b512, 0, stream>>>(qkvh, Mb, sbuf, 256, 1);
  k_deltaM<<<dim3(32, 2, 4), b512, 0, stream>>>(sbuf, qkvh, Mp, gamma, Mnext, Mnb);
  k_qM<<<dim3(32, 4, 2),     b512, 0, stream>>>(qkvh, Mnb, outf, 0, 0);
  k_out<<<dim3(128, 8),      b512, 0, stream>>>(outf, WoT, bo, out);
}